// Round 11
// baseline (681.917 us; speedup 1.0000x reference)
//
#include <hip/hip_runtime.h>
#include <hip/hip_bf16.h>

// Linear recurrence h_t = x_t@W + h_{t-1}@R, parallel scan, chunk C=8.
// Model (R10): all recurrence kernels bound by L2 frag-broadcast ~14.5 TB/s
// aggregate; currency = frag-bytes x CU-copies. R11 halves copies:
// - local: M=64 (2 chunks/block, 128 blocks), 8 single steps, writes y_j
//   (chunk-local solution) into out per step.
// - fix0 -> k_add: h_{8c+j} = y_j + E0[c]@R^(j+1): 1024 independent M=64
//   matmuls (chunk-pair x j), frags R^1..R^8 (R^3,5,6,7 from co-dispatched
//   extra power tasks). No serial chain.
// - xw / tree / chain / downs unchanged from R10.

typedef float f32x4 __attribute__((ext_vector_type(4)));
typedef __bf16 bf16x8 __attribute__((ext_vector_type(8)));

#define TDIM 2048L
#define UDIM 512L
#define ST32 16384L     // elems per [32,512] state
#define ST64 32768L     // elems per [64,512] tile
#define TS 262144L      // elems per frag term
#define FE 786432L      // elems per 3-term frag matrix
#define PP 520          // padded plane row stride (bf16 elems)

__device__ __forceinline__ f32x4 mfma16(bf16x8 a, bf16x8 b, f32x4 c) {
  return __builtin_amdgcn_mfma_f32_16x16x32_bf16(a, b, c, 0, 0, 0);
}

// fp32 [32][512] swizzle (sq staging)
__device__ __forceinline__ int hidx(int row, int col) {
  return row * 512 + (col ^ ((row & 7) << 3));
}

__device__ __forceinline__ void pack8(const f32x4& v0, const f32x4& v1,
                                      bf16x8& hv, bf16x8& lv) {
#pragma unroll
  for (int j = 0; j < 4; ++j) {
    const float a = v0[j];
    const __bf16 ha = (__bf16)a;
    hv[j] = ha; lv[j] = (__bf16)(a - (float)ha);
    const float b = v1[j];
    const __bf16 hb = (__bf16)b;
    hv[j + 4] = hb; lv[j + 4] = (__bf16)(b - (float)hb);
  }
}

// ---- M=64 pair-plane helpers (1024 thr) -----------------------------------
// Planes [64][PP]; rows 0-31 = chunk A (batch 0-31), rows 32-63 = chunk B.

// stage from out[B,T,U]: rows<32 at time tA, rows>=32 at time tB
__device__ __forceinline__ void stage_bt64(const float* __restrict__ out,
                                           long tA, long tB,
                                           __bf16* Phi, __bf16* Plo) {
  for (int i = threadIdx.x; i < 4096; i += 1024) {
    const int row = i >> 6, cb = i & 63;
    const int bat = row & 31;
    const long t = (row < 32) ? tA : tB;
    const float* src = out + (long)bat * (TDIM * UDIM) + t * UDIM + cb * 8;
    bf16x8 hv, lv;
    pack8(*(const f32x4*)src, *(const f32x4*)(src + 4), hv, lv);
    const int o = row * PP + cb * 8;
    *(bf16x8*)(Phi + o) = hv;
    *(bf16x8*)(Plo + o) = lv;
  }
}

// stage from contiguous [64,512]
__device__ __forceinline__ void stage64c(const float* __restrict__ src,
                                         __bf16* Phi, __bf16* Plo) {
  for (int i = threadIdx.x; i < 4096; i += 1024) {
    const int row = i >> 6, cb = i & 63;
    const float* p = src + (long)row * 512 + cb * 8;
    bf16x8 hv, lv;
    pack8(*(const f32x4*)p, *(const f32x4*)(p + 4), hv, lv);
    const int o = row * PP + cb * 8;
    *(bf16x8*)(Phi + o) = hv;
    *(bf16x8*)(Plo + o) = lv;
  }
}

// planes -> out[B,T,U] (store), rows<32 at tA, rows>=32 at tB
__device__ __forceinline__ void write_bt64(const __bf16* Phi, const __bf16* Plo,
                                           float* out, long tA, long tB) {
  for (int i = threadIdx.x; i < 4096; i += 1024) {
    const int row = i >> 6, cb = i & 63;
    const int o = row * PP + cb * 8;
    const bf16x8 hv = *(const bf16x8*)(Phi + o);
    const bf16x8 lv = *(const bf16x8*)(Plo + o);
    f32x4 o0, o1;
#pragma unroll
    for (int j = 0; j < 4; ++j) {
      o0[j] = (float)hv[j] + (float)lv[j];
      o1[j] = (float)hv[j + 4] + (float)lv[j + 4];
    }
    const int bat = row & 31;
    const long t = (row < 32) ? tA : tB;
    float* dst = out + (long)bat * (TDIM * UDIM) + t * UDIM + cb * 8;
    *(f32x4*)dst = o0;
    *(f32x4*)(dst + 4) = o1;
  }
}

// planes -> contiguous [64,512]
__device__ __forceinline__ void write_flat64(const __bf16* Phi, const __bf16* Plo,
                                             float* dst) {
  for (int i = threadIdx.x; i < 4096; i += 1024) {
    const int row = i >> 6, cb = i & 63;
    const int o = row * PP + cb * 8;
    const bf16x8 hv = *(const bf16x8*)(Phi + o);
    const bf16x8 lv = *(const bf16x8*)(Plo + o);
    f32x4 o0, o1;
#pragma unroll
    for (int j = 0; j < 4; ++j) {
      o0[j] = (float)hv[j] + (float)lv[j];
      o1[j] = (float)hv[j + 4] + (float)lv[j + 4];
    }
    float* d = dst + (long)row * 512 + cb * 8;
    *(f32x4*)d = o0;
    *(f32x4*)(d + 4) = o1;
  }
}

// One step on M=64 planes: h <- h@R + xw[t]; 16 waves, wave owns 2 nt.
template <int NPROD>
__device__ __forceinline__ void pstep64(__bf16* Phi, __bf16* Plo,
                                        const __bf16* __restrict__ bfrag,
                                        const float* __restrict__ xwb,
                                        long tA, long tB) {
  const int tid = threadIdx.x, l = tid & 63, w = tid >> 6, g = l >> 4, li = l & 15;
  f32x4 addv[4][2];
#pragma unroll
  for (int mt = 0; mt < 4; ++mt) {
    const long t = (mt < 2) ? tA : tB;
#pragma unroll
    for (int q = 0; q < 2; ++q) {
      const int col = (w * 2 + q) * 16 + li;
#pragma unroll
      for (int r = 0; r < 4; ++r) {
        const int bat = (mt & 1) * 16 + g * 4 + r;
        addv[mt][q][r] = xwb[(long)bat * (TDIM * UDIM) + t * UDIM + col];
      }
    }
  }
  f32x4 acc[4][2] = {};
#pragma unroll 2
  for (int kk = 0; kk < 16; ++kk) {
    bf16x8 b0[2], b1[2];
#pragma unroll
    for (int q = 0; q < 2; ++q) {
      const long fo = (((long)(w * 2 + q) * 16 + kk) * 64 + l) * 8;
      b0[q] = *(const bf16x8*)(bfrag + fo);
      b1[q] = *(const bf16x8*)(bfrag + TS + fo);
    }
#pragma unroll
    for (int mt = 0; mt < 4; ++mt) {
      const int o = (mt * 16 + li) * PP + kk * 32 + g * 8;
      const bf16x8 a1 = *(const bf16x8*)(Phi + o);
      const bf16x8 a2 = *(const bf16x8*)(Plo + o);
#pragma unroll
      for (int q = 0; q < 2; ++q) {
        acc[mt][q] = mfma16(a1, b0[q], acc[mt][q]);
        acc[mt][q] = mfma16(a1, b1[q], acc[mt][q]);
        if (NPROD >= 3) acc[mt][q] = mfma16(a2, b0[q], acc[mt][q]);
      }
    }
  }
  __syncthreads();  // plane reads done before overwrite
#pragma unroll
  for (int mt = 0; mt < 4; ++mt)
#pragma unroll
    for (int q = 0; q < 2; ++q) {
      const int col = (w * 2 + q) * 16 + li;
#pragma unroll
      for (int r = 0; r < 4; ++r) {
        const float v = acc[mt][q][r] + addv[mt][q][r];
        const int row = mt * 16 + g * 4 + r;
        const __bf16 hi = (__bf16)v;
        const int o = row * PP + col;
        Phi[o] = hi;
        Plo[o] = (__bf16)(v - (float)hi);
      }
    }
  __syncthreads();
}

// ---- device tasks ----------------------------------------------------------

// xW task, M=64: 512 thr = 8 waves; wave owns 4 nt; mt=0..3. 2 products.
__device__ __forceinline__ void xw_dev(long blk, const float* __restrict__ x,
                                       const __bf16* __restrict__ wf,
                                       float* __restrict__ out, char* smem) {
  __bf16* Phi = (__bf16*)smem;  // [64][PP] hi-only = 66560 B
  const float* src = x + blk * ST64;
  for (int i = threadIdx.x; i < 4096; i += 512) {
    const int row = i >> 6, cb = i & 63;
    const f32x4 v0 = *(const f32x4*)(src + (long)row * 512 + cb * 8);
    const f32x4 v1 = *(const f32x4*)(src + (long)row * 512 + cb * 8 + 4);
    bf16x8 hv;
#pragma unroll
    for (int j = 0; j < 4; ++j) {
      hv[j] = (__bf16)v0[j];
      hv[j + 4] = (__bf16)v1[j];
    }
    *(bf16x8*)(Phi + row * PP + cb * 8) = hv;
  }
  __syncthreads();
  const int tid = threadIdx.x, l = tid & 63, w = tid >> 6, g = l >> 4, li = l & 15;
  f32x4 acc[4][4] = {};
#pragma unroll 2
  for (int kk = 0; kk < 16; ++kk) {
    bf16x8 b0[4], b1[4];
#pragma unroll
    for (int q = 0; q < 4; ++q) {
      const long fo = (((long)(w * 4 + q) * 16 + kk) * 64 + l) * 8;
      b0[q] = *(const bf16x8*)(wf + fo);
      b1[q] = *(const bf16x8*)(wf + TS + fo);
    }
#pragma unroll
    for (int mt = 0; mt < 4; ++mt) {
      const bf16x8 a1 = *(const bf16x8*)(Phi + (mt * 16 + li) * PP + kk * 32 + g * 8);
#pragma unroll
      for (int q = 0; q < 4; ++q) {
        acc[mt][q] = mfma16(a1, b0[q], acc[mt][q]);
        acc[mt][q] = mfma16(a1, b1[q], acc[mt][q]);
      }
    }
  }
  float* gdst = out + blk * ST64;
#pragma unroll
  for (int mt = 0; mt < 4; ++mt)
#pragma unroll
    for (int q = 0; q < 4; ++q) {
      const int col = (w * 4 + q) * 16 + li;
#pragma unroll
      for (int r = 0; r < 4; ++r)
        gdst[(long)(mt * 16 + g * 4 + r) * 512 + col] = acc[mt][q][r];
    }
}

template <int NTERM, int NPROD>
__device__ __forceinline__ f32x4 one_mm(const float* __restrict__ a,
                                        const __bf16* __restrict__ bf,
                                        int mt, int ntg) {
  const int tid = threadIdx.x, l = tid & 63, g = (l >> 4) & 3, li = l & 15;
  f32x4 acc = {};
#pragma unroll 2
  for (int kk = 0; kk < 16; ++kk) {
    const long fo = (((long)ntg * 16 + kk) * 64 + l) * 8;
    const bf16x8 b0 = *(const bf16x8*)(bf + fo);
    const bf16x8 b1 = *(const bf16x8*)(bf + TS + fo);
    bf16x8 b2;
    if (NPROD >= 4) b2 = *(const bf16x8*)(bf + 2 * TS + fo);
    bf16x8 a1, a2;
    const float* p = a + (long)(mt * 16 + li) * 512 + kk * 32 + g * 8;
#pragma unroll
    for (int j = 0; j < 8; ++j) {
      const float v = p[j];
      const __bf16 hi = (__bf16)v;
      a1[j] = hi;
      a2[j] = (__bf16)(v - (float)hi);
    }
    acc = mfma16(a1, b0, acc);
    acc = mfma16(a1, b1, acc);
    if (NPROD >= 3) acc = mfma16(a2, b0, acc);
    if (NPROD >= 4) acc = mfma16(a1, b2, acc);
  }
  return acc;
}

// Squaring/multiply task (128 blocks x 512 thr): out = A @ Bfrag, fp32 +
// fused 3-term frag split of the result.
__device__ __forceinline__ void sq_dev(int b, const float* __restrict__ a,
                                       const __bf16* __restrict__ bf,
                                       float* __restrict__ of32,
                                       __bf16* __restrict__ ofr, float* hbuf) {
  const int rg = b >> 3, cg = b & 7;
  const int tid = threadIdx.x, l = tid & 63, w = tid >> 6, g = l >> 4, li = l & 15;
  const float* src = a + (long)rg * ST32;
  for (int i = tid; i < 4096; i += 512) {
    const int flat = i * 4, row = flat >> 9, col = flat & 511;
    *(f32x4*)&hbuf[hidx(row, col)] = *(const f32x4*)&src[flat];
  }
  __syncthreads();
  const int mt = w >> 2, q = w & 3, ntg = cg * 4 + q;
  f32x4 acc = {};
#pragma unroll 2
  for (int kk = 0; kk < 16; ++kk) {
    const long fo = (((long)ntg * 16 + kk) * 64 + l) * 8;
    const bf16x8 b0 = *(const bf16x8*)(bf + fo);
    const bf16x8 b1 = *(const bf16x8*)(bf + TS + fo);
    const bf16x8 b2 = *(const bf16x8*)(bf + 2 * TS + fo);
    bf16x8 a1, a2;
    const float* pp = &hbuf[hidx(mt * 16 + li, kk * 32 + g * 8)];
#pragma unroll
    for (int j = 0; j < 8; ++j) {
      const float v = pp[j];
      const __bf16 hi = (__bf16)v;
      a1[j] = hi;
      a2[j] = (__bf16)(v - (float)hi);
    }
    acc = mfma16(a1, b0, acc);
    acc = mfma16(a1, b1, acc);
    acc = mfma16(a2, b0, acc);
    acc = mfma16(a1, b2, acc);
  }
  const int n = ntg * 16 + li;
#pragma unroll
  for (int r = 0; r < 4; ++r) {
    const int k = rg * 32 + mt * 16 + g * 4 + r;
    const float v = acc[r];
    of32[(long)k * 512 + n] = v;
    const __bf16 t1 = (__bf16)v;
    const float r1 = v - (float)t1;
    const __bf16 t2 = (__bf16)r1;
    const long fi = (((long)(n >> 4) * 16 + (k >> 5)) * 64 + ((k >> 3) & 3) * 16 + (n & 15)) * 8 + (k & 7);
    ofr[fi] = t1;
    ofr[TS + fi] = t2;
    ofr[2 * TS + fi] = (__bf16)(r1 - (float)t2);
  }
}

// Tree up-stage task: out[p] = in[2p] @ M + in[2p+1] (col-slice cs).
__device__ __forceinline__ void pair_dev(int b, const float* __restrict__ in,
                                         const __bf16* __restrict__ bf,
                                         float* __restrict__ outb) {
  const int p = b >> 3, cs = b & 7;
  const int tid = threadIdx.x, l = tid & 63, w = tid >> 6, g = l >> 4, li = l & 15;
  const int mt = w >> 2, ntg = cs * 4 + (w & 3);
  const f32x4 acc = one_mm<2, 3>(in + (long)(2 * p) * ST32, bf, mt, ntg);
  const float* addp = in + (long)(2 * p + 1) * ST32;
  float* outp = outb + (long)p * ST32;
  const int col = ntg * 16 + li;
#pragma unroll
  for (int r = 0; r < 4; ++r) {
    const int row = mt * 16 + g * 4 + r;
    outp[(long)row * 512 + col] = acc[r] + addp[(long)row * 512 + col];
  }
}

// ---- kernels --------------------------------------------------------------

// Split two fp32 512x512 matrices into 3 bf16 terms (MFMA B-fragment order).
__global__ __launch_bounds__(512) void k_split2(const float* __restrict__ m0,
                                                const float* __restrict__ m1,
                                                __bf16* __restrict__ f0,
                                                __bf16* __restrict__ f1) {
  const int bb = blockIdx.x;
  const float* m = (bb < 512) ? m0 : m1;
  __bf16* f = (bb < 512) ? f0 : f1;
  const int idx = (bb & 511) * 512 + threadIdx.x;
  const int j = idx & 7, l = (idx >> 3) & 63, kk = (idx >> 9) & 15, nt = idx >> 13;
  const int k = kk * 32 + (l >> 4) * 8 + j;
  const int n = nt * 16 + (l & 15);
  const float v = m[k * 512 + n];
  const __bf16 t1 = (__bf16)v;
  const float r1 = v - (float)t1;
  const __bf16 t2 = (__bf16)r1;
  f[idx] = t1;
  f[TS + idx] = t2;
  f[2 * TS + idx] = (__bf16)(r1 - (float)t2);
}

// xW remainder kernel (base = first M=64 tile index).
__global__ __launch_bounds__(512) void k_xw(const float* __restrict__ x,
                                            const __bf16* __restrict__ wf,
                                            float* __restrict__ out, int base) {
  __shared__ __align__(16) char smem[64 * PP * 2];
  xw_dev(base + blockIdx.x, x, wf, out, smem);
}

// Co-dispatch: b<128 sq chain; (pwEn && b<256) extra power; else xw tiles.
__global__ __launch_bounds__(512) void k_xwsq(const float* __restrict__ sqa,
                                              const __bf16* __restrict__ sqbf,
                                              float* __restrict__ sqo32,
                                              __bf16* __restrict__ sqofr,
                                              const float* __restrict__ pwa,
                                              const __bf16* __restrict__ pwbf,
                                              float* __restrict__ pwo32,
                                              __bf16* __restrict__ pwofr,
                                              const float* __restrict__ x,
                                              const __bf16* __restrict__ wf,
                                              float* __restrict__ out,
                                              int base, int pwEn) {
  __shared__ __align__(16) char smem[64 * PP * 2];
  const int b = blockIdx.x;
  if (b < 128)
    sq_dev(b, sqa, sqbf, sqo32, sqofr, (float*)smem);
  else if (pwEn && b < 256)
    sq_dev(b - 128, pwa, pwbf, pwo32, pwofr, (float*)smem);
  else
    xw_dev(base + (b - (pwEn ? 256 : 128)), x, wf, out, smem);
}

// Co-dispatch: b<128 sq; (pwEn && b<256) power; else tree up-stage.
__global__ __launch_bounds__(512) void k_combo(const float* __restrict__ sqa,
                                               const __bf16* __restrict__ sqbf,
                                               float* __restrict__ sqo32,
                                               __bf16* __restrict__ sqofr,
                                               const float* __restrict__ pwa,
                                               const __bf16* __restrict__ pwbf,
                                               float* __restrict__ pwo32,
                                               __bf16* __restrict__ pwofr,
                                               const float* __restrict__ prin,
                                               const __bf16* __restrict__ prbf,
                                               float* __restrict__ prout,
                                               int pwEn) {
  __shared__ float hbuf[ST32];
  const int b = blockIdx.x;
  if (b < 128)
    sq_dev(b, sqa, sqbf, sqo32, sqofr, hbuf);
  else if (pwEn && b < 256)
    sq_dev(b - 128, pwa, pwbf, pwo32, pwofr, hbuf);
  else
    pair_dev(b - (pwEn ? 256 : 128), prin, prbf, prout);
}

// Level-0: M=64 (chunks 2b, 2b+1), 8 single steps; writes y_j into out
// (j>=1; y_0 = xw already there) and chunk sums into Sbuf.
__global__ __launch_bounds__(1024) void k_local64(float* out,
                                                  const __bf16* __restrict__ rf,
                                                  float* __restrict__ sout) {
  __shared__ __bf16 Phi[64 * PP], Plo[64 * PP];
  const long c0 = 2L * blockIdx.x;
  stage_bt64(out, c0 * 8, (c0 + 1) * 8, Phi, Plo);  // y_0 = xw
  __syncthreads();
  for (int j = 1; j < 8; ++j) {
    pstep64<3>(Phi, Plo, rf, out, c0 * 8 + j, (c0 + 1) * 8 + j);
    write_bt64(Phi, Plo, out, c0 * 8 + j, (c0 + 1) * 8 + j);
  }
  write_flat64(Phi, Plo, sout + c0 * ST32);  // S[c0], S[c0+1]
}

// Fix pass: out[t] += E0[c] @ R^(j+1), M=64 chunk-pairs, fully parallel.
// Grid 1024: b = pair*8 + j. R^(j+1) frag index: {0,1,11,2,12,13,14,3}.
__global__ __launch_bounds__(1024) void k_add(const float* __restrict__ e0,
                                              float* out,
                                              const __bf16* __restrict__ F) {
  __shared__ __bf16 Phi[64 * PP], Plo[64 * PP];
  const int b = blockIdx.x, pi = b >> 3, j = b & 7;
  int fi;
  switch (j) {
    case 0: fi = 0; break;  case 1: fi = 1; break;
    case 2: fi = 11; break; case 3: fi = 2; break;
    case 4: fi = 12; break; case 5: fi = 13; break;
    case 6: fi = 14; break; default: fi = 3; break;
  }
  const __bf16* bf = F + (long)fi * FE;
  stage64c(e0 + (long)pi * 2 * ST32, Phi, Plo);
  __syncthreads();
  const int tid = threadIdx.x, l = tid & 63, w = tid >> 6, g = l >> 4, li = l & 15;
  f32x4 acc[4][2] = {};
#pragma unroll 2
  for (int kk = 0; kk < 16; ++kk) {
    bf16x8 b0[2], b1[2];
#pragma unroll
    for (int q = 0; q < 2; ++q) {
      const long fo = (((long)(w * 2 + q) * 16 + kk) * 64 + l) * 8;
      b0[q] = *(const bf16x8*)(bf + fo);
      b1[q] = *(const bf16x8*)(bf + TS + fo);
    }
#pragma unroll
    for (int mt = 0; mt < 4; ++mt) {
      const int o = (mt * 16 + li) * PP + kk * 32 + g * 8;
      const bf16x8 a1 = *(const bf16x8*)(Phi + o);
      const bf16x8 a2 = *(const bf16x8*)(Plo + o);
#pragma unroll
      for (int q = 0; q < 2; ++q) {
        acc[mt][q] = mfma16(a1, b0[q], acc[mt][q]);
        acc[mt][q] = mfma16(a1, b1[q], acc[mt][q]);
        acc[mt][q] = mfma16(a2, b0[q], acc[mt][q]);
      }
    }
  }
  __syncthreads();  // e-plane reads done
#pragma unroll
  for (int mt = 0; mt < 4; ++mt)
#pragma unroll
    for (int q = 0; q < 2; ++q) {
      const int col = (w * 2 + q) * 16 + li;
#pragma unroll
      for (int r = 0; r < 4; ++r) {
        const float v = acc[mt][q][r];
        const int row = mt * 16 + g * 4 + r;
        const __bf16 hi = (__bf16)v;
        const int o = row * PP + col;
        Phi[o] = hi;
        Plo[o] = (__bf16)(v - (float)hi);
      }
    }
  __syncthreads();
  // out[t] = y (already there) + e@R^(j+1), coalesced RMW rows
  const long tA = (2L * pi) * 8 + j, tB = (2L * pi + 1) * 8 + j;
  for (int i = threadIdx.x; i < 4096; i += 1024) {
    const int row = i >> 6, cb = i & 63;
    const int o = row * PP + cb * 8;
    const bf16x8 hv = *(const bf16x8*)(Phi + o);
    const bf16x8 lv = *(const bf16x8*)(Plo + o);
    const int bat = row & 31;
    const long t = (row < 32) ? tA : tB;
    float* dst = out + (long)bat * (TDIM * UDIM) + t * UDIM + cb * 8;
    f32x4 a0 = *(const f32x4*)dst;
    f32x4 a1v = *(const f32x4*)(dst + 4);
#pragma unroll
    for (int jj = 0; jj < 4; ++jj) {
      a0[jj] += (float)hv[jj] + (float)lv[jj];
      a1v[jj] += (float)hv[jj + 4] + (float)lv[jj + 4];
    }
    *(f32x4*)dst = a0;
    *(f32x4*)(dst + 4) = a1v;
  }
}

// Tree down-stage (in place into child-level buffer):
//   ulev[2p+1] = epar[p] @ M + ulev[2p];  ulev[2p] = epar[p]
__global__ __launch_bounds__(512) void k_down(const float* __restrict__ epar,
                                              float* __restrict__ ulev,
                                              const __bf16* __restrict__ bf) {
  const int p = blockIdx.x >> 3, cs = blockIdx.x & 7;
  const int tid = threadIdx.x, l = tid & 63, w = tid >> 6, g = l >> 4, li = l & 15;
  const int mt = w >> 2, ntg = cs * 4 + (w & 3);
  const f32x4 acc = one_mm<2, 3>(epar + (long)p * ST32, bf, mt, ntg);
  float* evp = ulev + (long)(2 * p) * ST32;
  float* outp = ulev + (long)(2 * p + 1) * ST32;
  const int col = ntg * 16 + li;
  float cp[4];
#pragma unroll
  for (int r = 0; r < 4; ++r) {
    const int row = mt * 16 + g * 4 + r;
    const long off = (long)row * 512 + col;
    cp[r] = epar[(long)p * ST32 + off];
    outp[off] = acc[r] + evp[off];
  }
  __syncthreads();
#pragma unroll
  for (int r = 0; r < 4; ++r) {
    const int row = mt * 16 + g * 4 + r;
    evp[(long)row * 512 + col] = cp[r];
  }
}

extern "C" void kernel_launch(void* const* d_in, const int* in_sizes, int n_in,
                              void* d_out, int out_size, void* d_ws, size_t ws_size,
                              hipStream_t stream) {
  (void)in_sizes; (void)n_in; (void)out_size; (void)ws_size;
  const float* x  = (const float*)d_in[0];
  const float* W  = (const float*)d_in[1];
  const float* R  = (const float*)d_in[2];
  const float* h0 = (const float*)d_in[3];
  float* out = (float*)d_out;

  // F[0..10] = frags of R^(2^i); F[11..14] = frags of R^3, R^5, R^6, R^7.
  __bf16* F  = (__bf16*)d_ws;
  __bf16* Fw = F + 15 * FE;            // frags of W
  float* P1 = (float*)(Fw + FE);
  float* P2 = P1 + TS;
  float* P3 = P2 + TS;                 // fp32 scratch for power tasks
  float* Sbuf = P3 + TS;               // 256 chunk sums -> entries E0
  float* Ub[8];
  {
    float* up = Sbuf + 256 * ST32;
    for (int k = 1; k <= 7; ++k) { Ub[k] = up; up += (1L << (8 - k)) * ST32; }
  }

  k_split2<<<1024, 512, 0, stream>>>(W, R, Fw, F);

  // Head: sq chain + extra powers co-dispatched with xw slices.
  //   phase1: F[1]=R^2                         + xw[0..255]
  //   phase2: F[2]=R^4  | F[11]=R^3 (R@F[1])   + xw[256..511]
  //   phase3: F[3]=R^8  | F[12]=R^5 (R@F[2])   + xw[512..767]
  k_xwsq<<<384, 512, 0, stream>>>(R, F, P1, F + FE,
                                  R, F, P3, F + 11L * FE,   // unused (pwEn=0)
                                  x, Fw, out, 0, 0);
  k_xwsq<<<512, 512, 0, stream>>>(P1, F + FE, P2, F + 2L * FE,
                                  R, F + FE, P3, F + 11L * FE,
                                  x, Fw, out, 256, 1);
  k_xwsq<<<512, 512, 0, stream>>>(P2, F + 2L * FE, P1, F + 3L * FE,
                                  R, F + 2L * FE, P3, F + 12L * FE,
                                  x, Fw, out, 512, 1);
  k_xw<<<256, 512, 0, stream>>>(x, Fw, out, 768);

  k_local64<<<128, 1024, 0, stream>>>(out, F, Sbuf);

  // phases k=1..7: sq (F[k+3] <- F[k+2]) | powers (k=1: R^6, k=2: R^7)
  //                | tree-up stage k (uses F[k+2])
  for (int k = 1; k <= 7; ++k) {
    const int i = k + 3;
    const float* sqa = (i & 1) ? P2 : P1;
    float* sqo = (i & 1) ? P1 : P2;
    const float* prin = (k == 1) ? Sbuf : Ub[k - 1];
    const int npr = (1 << (8 - k)) * 8;
    const int pwEn = (k <= 2) ? 1 : 0;
    const __bf16* pwbf = (k == 1) ? (F + 12L * FE) : (F + 13L * FE);
    __bf16* pwofr = (k == 1) ? (F + 13L * FE) : (F + 14L * FE);
    k_combo<<<128 + (pwEn ? 128 : 0) + npr, 512, 0, stream>>>(
        sqa, F + (long)(i - 1) * FE, sqo, F + (long)i * FE,
        R, pwbf, P3, pwofr,
        prin, F + (long)(k + 2) * FE, Ub[k], pwEn);
  }

  // down-sweep: entries, in place into each child level (E0 lands in Sbuf)
  k_down<<<8, 512, 0, stream>>>(h0, Ub[7], F + 10L * FE);
  for (int k = 7; k >= 1; --k) {
    float* ul = (k == 1) ? Sbuf : Ub[k - 1];
    k_down<<<(1 << (8 - k)) * 8, 512, 0, stream>>>(Ub[k], ul, F + (long)(k + 2) * FE);
  }

  // fix: out[t] = y_t + E0[c]@R^(j+1)
  k_add<<<1024, 1024, 0, stream>>>(Sbuf, out, F);
}

// Round 12
// 649.133 us; speedup vs baseline: 1.0505x; 1.0505x over previous
//
#include <hip/hip_runtime.h>
#include <hip/hip_bf16.h>

// Linear recurrence h_t = x_t@W + h_{t-1}@R, parallel scan, chunk C=8.
// R12 = R8 skeleton + even/odd fix decomposition (R11-verified math):
// - local (R8-proven): 256 blocks, M=32, 1 single + 3 double steps; now also
//   writes y_j to out at j in {1,3,5,7} (xw stays at j in {0,2,4,6}).
// - fix0 replaced by two parallel passes:
//     k_add5: out[8c+j] += E0[c] @ R^(j+1), j in {0,1,3,5,7}  (640 blocks)
//     k_odd:  out[t]    += h_{t-1} @ R,     j in {2,4,6}      (384 blocks)
//   R^6 = R^4 @ R^2 co-dispatched into combo phase k=1.
// - xw / chain / tree / downs byte-identical to R8 (607us).

typedef float f32x4 __attribute__((ext_vector_type(4)));
typedef __bf16 bf16x8 __attribute__((ext_vector_type(8)));

#define TDIM 2048L
#define UDIM 512L
#define ST32 16384L     // elems per [32,512] state
#define ST64 32768L     // elems per [64,512] tile
#define TS 262144L      // elems per frag term
#define FE 786432L      // elems per 3-term frag matrix
#define PP 520          // padded plane row stride (bf16 elems)

__device__ __forceinline__ f32x4 mfma16(bf16x8 a, bf16x8 b, f32x4 c) {
  return __builtin_amdgcn_mfma_f32_16x16x32_bf16(a, b, c, 0, 0, 0);
}

// fp32 [32][512] swizzle (sq staging)
__device__ __forceinline__ int hidx(int row, int col) {
  return row * 512 + (col ^ ((row & 7) << 3));
}

__device__ __forceinline__ void pack8(const f32x4& v0, const f32x4& v1,
                                      bf16x8& hv, bf16x8& lv) {
#pragma unroll
  for (int j = 0; j < 4; ++j) {
    const float a = v0[j];
    const __bf16 ha = (__bf16)a;
    hv[j] = ha; lv[j] = (__bf16)(a - (float)ha);
    const float b = v1[j];
    const __bf16 hb = (__bf16)b;
    hv[j + 4] = hb; lv[j + 4] = (__bf16)(b - (float)hb);
  }
}

// ---- M=32 pair-plane helpers (stride PP, blockDim-stride loops) -----------

__device__ __forceinline__ void stage32p(const float* __restrict__ src,
                                         long pitch, __bf16* Phi, __bf16* Plo) {
  for (int i = threadIdx.x; i < 2048; i += blockDim.x) {
    const int row = i >> 6, cb = i & 63;
    const float* p = src + (long)row * pitch + cb * 8;
    bf16x8 hv, lv;
    pack8(*(const f32x4*)p, *(const f32x4*)(p + 4), hv, lv);
    const int o = row * PP + cb * 8;
    *(bf16x8*)(Phi + o) = hv;
    *(bf16x8*)(Plo + o) = lv;
  }
}

__device__ __forceinline__ void write_bt(const __bf16* Phi, const __bf16* Plo,
                                         float* out, long t) {
  for (int i = threadIdx.x; i < 2048; i += blockDim.x) {
    const int row = i >> 6, cb = i & 63;
    const int o = row * PP + cb * 8;
    const bf16x8 hv = *(const bf16x8*)(Phi + o);
    const bf16x8 lv = *(const bf16x8*)(Plo + o);
    f32x4 o0, o1;
#pragma unroll
    for (int j = 0; j < 4; ++j) {
      o0[j] = (float)hv[j] + (float)lv[j];
      o1[j] = (float)hv[j + 4] + (float)lv[j + 4];
    }
    float* dst = out + (long)row * (TDIM * UDIM) + t * UDIM + cb * 8;
    *(f32x4*)dst = o0;
    *(f32x4*)(dst + 4) = o1;
  }
}

__device__ __forceinline__ void write_flat(const __bf16* Phi, const __bf16* Plo,
                                           float* dst) {
  for (int i = threadIdx.x; i < 2048; i += blockDim.x) {
    const int row = i >> 6, cb = i & 63;
    const int o = row * PP + cb * 8;
    const bf16x8 hv = *(const bf16x8*)(Phi + o);
    const bf16x8 lv = *(const bf16x8*)(Plo + o);
    f32x4 o0, o1;
#pragma unroll
    for (int j = 0; j < 4; ++j) {
      o0[j] = (float)hv[j] + (float)lv[j];
      o1[j] = (float)hv[j + 4] + (float)lv[j + 4];
    }
    float* d = dst + row * 512 + cb * 8;
    *(f32x4*)d = o0;
    *(f32x4*)(d + 4) = o1;
  }
}

// One step on M=32 planes (1024 thr, 16 waves, wave owns 2 nt)
template <int NTERM, int NPROD, bool HAS_H>
__device__ __forceinline__ void pstep32(__bf16* Phi, __bf16* Plo,
                                        const __bf16* __restrict__ bfrag,
                                        const float* __restrict__ xwbase, long t) {
  const int tid = threadIdx.x, l = tid & 63, w = tid >> 6, g = l >> 4, li = l & 15;
  f32x4 addv[2][2];
#pragma unroll
  for (int mt = 0; mt < 2; ++mt)
#pragma unroll
    for (int q = 0; q < 2; ++q) {
      const int col = (w * 2 + q) * 16 + li;
#pragma unroll
      for (int r = 0; r < 4; ++r) {
        const int bat = mt * 16 + g * 4 + r;
        addv[mt][q][r] = xwbase[(long)bat * (TDIM * UDIM) + t * UDIM + col];
      }
    }

  f32x4 acc[2][2] = {};
  if (HAS_H) {
#pragma unroll 2
    for (int kk = 0; kk < 16; ++kk) {
      bf16x8 b[NTERM][2];
#pragma unroll
      for (int q = 0; q < 2; ++q) {
        const long fo = (((long)(w * 2 + q) * 16 + kk) * 64 + l) * 8;
#pragma unroll
        for (int tt = 0; tt < NTERM; ++tt)
          b[tt][q] = *(const bf16x8*)(bfrag + (long)tt * TS + fo);
      }
#pragma unroll
      for (int mt = 0; mt < 2; ++mt) {
        const int o = (mt * 16 + li) * PP + kk * 32 + g * 8;
        const bf16x8 a1 = *(const bf16x8*)(Phi + o);
        const bf16x8 a2 = *(const bf16x8*)(Plo + o);
#pragma unroll
        for (int q = 0; q < 2; ++q) {
          acc[mt][q] = mfma16(a1, b[0][q], acc[mt][q]);
          acc[mt][q] = mfma16(a1, b[1][q], acc[mt][q]);
          if (NPROD >= 3) acc[mt][q] = mfma16(a2, b[0][q], acc[mt][q]);
          if (NPROD >= 4) acc[mt][q] = mfma16(a1, b[NTERM - 1][q], acc[mt][q]);
        }
      }
    }
    __syncthreads();  // plane reads done before overwrite
  }

#pragma unroll
  for (int mt = 0; mt < 2; ++mt)
#pragma unroll
    for (int q = 0; q < 2; ++q) {
      const int col = (w * 2 + q) * 16 + li;
#pragma unroll
      for (int r = 0; r < 4; ++r) {
        const float v = (HAS_H ? acc[mt][q][r] : 0.0f) + addv[mt][q][r];
        const int row = mt * 16 + g * 4 + r;
        const __bf16 hi = (__bf16)v;
        const int o = row * PP + col;
        Phi[o] = hi;
        Plo[o] = (__bf16)(v - (float)hi);
      }
    }
  __syncthreads();
}

// Double step: h <- h@R^2 + xw[t1]@R + xw[t2]  (k_local, 1024 thr)
__device__ __forceinline__ void dstep(__bf16* Phi, __bf16* Plo,
                                      __bf16* Qhi, __bf16* Qlo,
                                      const __bf16* __restrict__ r2f,
                                      const __bf16* __restrict__ rf,
                                      const float* __restrict__ xw,
                                      long t1, long t2) {
  stage32p(xw + t1 * UDIM, TDIM * UDIM, Qhi, Qlo);
  __syncthreads();
  const int tid = threadIdx.x, l = tid & 63, w = tid >> 6, g = l >> 4, li = l & 15;
  f32x4 addv[2][2];
#pragma unroll
  for (int mt = 0; mt < 2; ++mt)
#pragma unroll
    for (int q = 0; q < 2; ++q) {
      const int col = (w * 2 + q) * 16 + li;
#pragma unroll
      for (int r = 0; r < 4; ++r) {
        const int bat = mt * 16 + g * 4 + r;
        addv[mt][q][r] = xw[(long)bat * (TDIM * UDIM) + t2 * UDIM + col];
      }
    }
  f32x4 acc[2][2] = {};
#pragma unroll 2
  for (int kk = 0; kk < 16; ++kk) {
    bf16x8 c0[2], c1[2], d0[2], d1[2];
#pragma unroll
    for (int q = 0; q < 2; ++q) {
      const long fo = (((long)(w * 2 + q) * 16 + kk) * 64 + l) * 8;
      c0[q] = *(const bf16x8*)(r2f + fo);
      c1[q] = *(const bf16x8*)(r2f + TS + fo);
      d0[q] = *(const bf16x8*)(rf + fo);
      d1[q] = *(const bf16x8*)(rf + TS + fo);
    }
#pragma unroll
    for (int mt = 0; mt < 2; ++mt) {
      const int o = (mt * 16 + li) * PP + kk * 32 + g * 8;
      const bf16x8 h1 = *(const bf16x8*)(Phi + o);
      const bf16x8 h2 = *(const bf16x8*)(Plo + o);
      const bf16x8 q1 = *(const bf16x8*)(Qhi + o);
      const bf16x8 q2 = *(const bf16x8*)(Qlo + o);
#pragma unroll
      for (int q = 0; q < 2; ++q) {
        acc[mt][q] = mfma16(h1, c0[q], acc[mt][q]);
        acc[mt][q] = mfma16(q1, d0[q], acc[mt][q]);
        acc[mt][q] = mfma16(h1, c1[q], acc[mt][q]);
        acc[mt][q] = mfma16(q1, d1[q], acc[mt][q]);
        acc[mt][q] = mfma16(h2, c0[q], acc[mt][q]);
        acc[mt][q] = mfma16(q2, d0[q], acc[mt][q]);
      }
    }
  }
  __syncthreads();
#pragma unroll
  for (int mt = 0; mt < 2; ++mt)
#pragma unroll
    for (int q = 0; q < 2; ++q) {
      const int col = (w * 2 + q) * 16 + li;
#pragma unroll
      for (int r = 0; r < 4; ++r) {
        const float v = acc[mt][q][r] + addv[mt][q][r];
        const int row = mt * 16 + g * 4 + r;
        const __bf16 hi = (__bf16)v;
        const int o = row * PP + col;
        Phi[o] = hi;
        Plo[o] = (__bf16)(v - (float)hi);
      }
    }
  __syncthreads();
}

// ---- M=64 helpers (1024 thr) ----------------------------------------------

// stage from out[B,T,U]: rows<32 at time tA, rows>=32 at time tB
__device__ __forceinline__ void stage_bt64(const float* __restrict__ out,
                                           long tA, long tB,
                                           __bf16* Phi, __bf16* Plo) {
  for (int i = threadIdx.x; i < 4096; i += 1024) {
    const int row = i >> 6, cb = i & 63;
    const int bat = row & 31;
    const long t = (row < 32) ? tA : tB;
    const float* src = out + (long)bat * (TDIM * UDIM) + t * UDIM + cb * 8;
    bf16x8 hv, lv;
    pack8(*(const f32x4*)src, *(const f32x4*)(src + 4), hv, lv);
    const int o = row * PP + cb * 8;
    *(bf16x8*)(Phi + o) = hv;
    *(bf16x8*)(Plo + o) = lv;
  }
}

// stage from contiguous [64,512]
__device__ __forceinline__ void stage64c(const float* __restrict__ src,
                                         __bf16* Phi, __bf16* Plo) {
  for (int i = threadIdx.x; i < 4096; i += 1024) {
    const int row = i >> 6, cb = i & 63;
    const float* p = src + (long)row * 512 + cb * 8;
    bf16x8 hv, lv;
    pack8(*(const f32x4*)p, *(const f32x4*)(p + 4), hv, lv);
    const int o = row * PP + cb * 8;
    *(bf16x8*)(Phi + o) = hv;
    *(bf16x8*)(Plo + o) = lv;
  }
}

// planes = planes @ bf (2-term, 3 products), then out[t] += planes (RMW).
__device__ __forceinline__ void mul_rmw64(__bf16* Phi, __bf16* Plo,
                                          const __bf16* __restrict__ bf,
                                          float* out, long tA, long tB) {
  const int tid = threadIdx.x, l = tid & 63, w = tid >> 6, g = l >> 4, li = l & 15;
  f32x4 acc[4][2] = {};
#pragma unroll 2
  for (int kk = 0; kk < 16; ++kk) {
    bf16x8 b0[2], b1[2];
#pragma unroll
    for (int q = 0; q < 2; ++q) {
      const long fo = (((long)(w * 2 + q) * 16 + kk) * 64 + l) * 8;
      b0[q] = *(const bf16x8*)(bf + fo);
      b1[q] = *(const bf16x8*)(bf + TS + fo);
    }
#pragma unroll
    for (int mt = 0; mt < 4; ++mt) {
      const int o = (mt * 16 + li) * PP + kk * 32 + g * 8;
      const bf16x8 a1 = *(const bf16x8*)(Phi + o);
      const bf16x8 a2 = *(const bf16x8*)(Plo + o);
#pragma unroll
      for (int q = 0; q < 2; ++q) {
        acc[mt][q] = mfma16(a1, b0[q], acc[mt][q]);
        acc[mt][q] = mfma16(a1, b1[q], acc[mt][q]);
        acc[mt][q] = mfma16(a2, b0[q], acc[mt][q]);
      }
    }
  }
  __syncthreads();  // plane reads done
#pragma unroll
  for (int mt = 0; mt < 4; ++mt)
#pragma unroll
    for (int q = 0; q < 2; ++q) {
      const int col = (w * 2 + q) * 16 + li;
#pragma unroll
      for (int r = 0; r < 4; ++r) {
        const float v = acc[mt][q][r];
        const int row = mt * 16 + g * 4 + r;
        const __bf16 hi = (__bf16)v;
        const int o = row * PP + col;
        Phi[o] = hi;
        Plo[o] = (__bf16)(v - (float)hi);
      }
    }
  __syncthreads();
  for (int i = threadIdx.x; i < 4096; i += 1024) {
    const int row = i >> 6, cb = i & 63;
    const int o = row * PP + cb * 8;
    const bf16x8 hv = *(const bf16x8*)(Phi + o);
    const bf16x8 lv = *(const bf16x8*)(Plo + o);
    const int bat = row & 31;
    const long t = (row < 32) ? tA : tB;
    float* dst = out + (long)bat * (TDIM * UDIM) + t * UDIM + cb * 8;
    f32x4 a0 = *(const f32x4*)dst;
    f32x4 a1v = *(const f32x4*)(dst + 4);
#pragma unroll
    for (int jj = 0; jj < 4; ++jj) {
      a0[jj] += (float)hv[jj] + (float)lv[jj];
      a1v[jj] += (float)hv[jj + 4] + (float)lv[jj + 4];
    }
    *(f32x4*)dst = a0;
    *(f32x4*)(dst + 4) = a1v;
  }
}

// ---- device tasks ----------------------------------------------------------

// xW task, M=64: 512 thr = 8 waves; wave owns 4 nt; mt=0..3. 2 products.
__device__ __forceinline__ void xw_dev(long blk, const float* __restrict__ x,
                                       const __bf16* __restrict__ wf,
                                       float* __restrict__ out, char* smem) {
  __bf16* Phi = (__bf16*)smem;  // [64][PP] hi-only = 66560 B
  const float* src = x + blk * ST64;
  for (int i = threadIdx.x; i < 4096; i += 512) {
    const int row = i >> 6, cb = i & 63;
    const f32x4 v0 = *(const f32x4*)(src + (long)row * 512 + cb * 8);
    const f32x4 v1 = *(const f32x4*)(src + (long)row * 512 + cb * 8 + 4);
    bf16x8 hv;
#pragma unroll
    for (int j = 0; j < 4; ++j) {
      hv[j] = (__bf16)v0[j];
      hv[j + 4] = (__bf16)v1[j];
    }
    *(bf16x8*)(Phi + row * PP + cb * 8) = hv;
  }
  __syncthreads();
  const int tid = threadIdx.x, l = tid & 63, w = tid >> 6, g = l >> 4, li = l & 15;
  f32x4 acc[4][4] = {};
#pragma unroll 2
  for (int kk = 0; kk < 16; ++kk) {
    bf16x8 b0[4], b1[4];
#pragma unroll
    for (int q = 0; q < 4; ++q) {
      const long fo = (((long)(w * 4 + q) * 16 + kk) * 64 + l) * 8;
      b0[q] = *(const bf16x8*)(wf + fo);
      b1[q] = *(const bf16x8*)(wf + TS + fo);
    }
#pragma unroll
    for (int mt = 0; mt < 4; ++mt) {
      const bf16x8 a1 = *(const bf16x8*)(Phi + (mt * 16 + li) * PP + kk * 32 + g * 8);
#pragma unroll
      for (int q = 0; q < 4; ++q) {
        acc[mt][q] = mfma16(a1, b0[q], acc[mt][q]);
        acc[mt][q] = mfma16(a1, b1[q], acc[mt][q]);
      }
    }
  }
  float* gdst = out + blk * ST64;
#pragma unroll
  for (int mt = 0; mt < 4; ++mt)
#pragma unroll
    for (int q = 0; q < 4; ++q) {
      const int col = (w * 4 + q) * 16 + li;
#pragma unroll
      for (int r = 0; r < 4; ++r)
        gdst[(long)(mt * 16 + g * 4 + r) * 512 + col] = acc[mt][q][r];
    }
}

template <int NTERM, int NPROD>
__device__ __forceinline__ f32x4 one_mm(const float* __restrict__ a,
                                        const __bf16* __restrict__ bf,
                                        int mt, int ntg) {
  const int tid = threadIdx.x, l = tid & 63, g = (l >> 4) & 3, li = l & 15;
  f32x4 acc = {};
#pragma unroll 2
  for (int kk = 0; kk < 16; ++kk) {
    const long fo = (((long)ntg * 16 + kk) * 64 + l) * 8;
    const bf16x8 b0 = *(const bf16x8*)(bf + fo);
    const bf16x8 b1 = *(const bf16x8*)(bf + TS + fo);
    bf16x8 b2;
    if (NPROD >= 4) b2 = *(const bf16x8*)(bf + 2 * TS + fo);
    bf16x8 a1, a2;
    const float* p = a + (long)(mt * 16 + li) * 512 + kk * 32 + g * 8;
#pragma unroll
    for (int j = 0; j < 8; ++j) {
      const float v = p[j];
      const __bf16 hi = (__bf16)v;
      a1[j] = hi;
      a2[j] = (__bf16)(v - (float)hi);
    }
    acc = mfma16(a1, b0, acc);
    acc = mfma16(a1, b1, acc);
    if (NPROD >= 3) acc = mfma16(a2, b0, acc);
    if (NPROD >= 4) acc = mfma16(a1, b2, acc);
  }
  return acc;
}

// Multiply task (128 blocks x 512 thr): out = A @ Bfrag, fp32 + frag split.
__device__ __forceinline__ void sq_dev(int b, const float* __restrict__ a,
                                       const __bf16* __restrict__ bf,
                                       float* __restrict__ of32,
                                       __bf16* __restrict__ ofr, float* hbuf) {
  const int rg = b >> 3, cg = b & 7;
  const int tid = threadIdx.x, l = tid & 63, w = tid >> 6, g = l >> 4, li = l & 15;
  const float* src = a + (long)rg * ST32;
  for (int i = tid; i < 4096; i += 512) {
    const int flat = i * 4, row = flat >> 9, col = flat & 511;
    *(f32x4*)&hbuf[hidx(row, col)] = *(const f32x4*)&src[flat];
  }
  __syncthreads();
  const int mt = w >> 2, q = w & 3, ntg = cg * 4 + q;
  f32x4 acc = {};
#pragma unroll 2
  for (int kk = 0; kk < 16; ++kk) {
    const long fo = (((long)ntg * 16 + kk) * 64 + l) * 8;
    const bf16x8 b0 = *(const bf16x8*)(bf + fo);
    const bf16x8 b1 = *(const bf16x8*)(bf + TS + fo);
    const bf16x8 b2 = *(const bf16x8*)(bf + 2 * TS + fo);
    bf16x8 a1, a2;
    const float* pp = &hbuf[hidx(mt * 16 + li, kk * 32 + g * 8)];
#pragma unroll
    for (int j = 0; j < 8; ++j) {
      const float v = pp[j];
      const __bf16 hi = (__bf16)v;
      a1[j] = hi;
      a2[j] = (__bf16)(v - (float)hi);
    }
    acc = mfma16(a1, b0, acc);
    acc = mfma16(a1, b1, acc);
    acc = mfma16(a2, b0, acc);
    acc = mfma16(a1, b2, acc);
  }
  const int n = ntg * 16 + li;
#pragma unroll
  for (int r = 0; r < 4; ++r) {
    const int k = rg * 32 + mt * 16 + g * 4 + r;
    const float v = acc[r];
    of32[(long)k * 512 + n] = v;
    const __bf16 t1 = (__bf16)v;
    const float r1 = v - (float)t1;
    const __bf16 t2 = (__bf16)r1;
    const long fi = (((long)(n >> 4) * 16 + (k >> 5)) * 64 + ((k >> 3) & 3) * 16 + (n & 15)) * 8 + (k & 7);
    ofr[fi] = t1;
    ofr[TS + fi] = t2;
    ofr[2 * TS + fi] = (__bf16)(r1 - (float)t2);
  }
}

// Tree up-stage task: out[p] = in[2p] @ M + in[2p+1] (col-slice cs).
__device__ __forceinline__ void pair_dev(int b, const float* __restrict__ in,
                                         const __bf16* __restrict__ bf,
                                         float* __restrict__ outb) {
  const int p = b >> 3, cs = b & 7;
  const int tid = threadIdx.x, l = tid & 63, w = tid >> 6, g = l >> 4, li = l & 15;
  const int mt = w >> 2, ntg = cs * 4 + (w & 3);
  const f32x4 acc = one_mm<2, 3>(in + (long)(2 * p) * ST32, bf, mt, ntg);
  const float* addp = in + (long)(2 * p + 1) * ST32;
  float* outp = outb + (long)p * ST32;
  const int col = ntg * 16 + li;
#pragma unroll
  for (int r = 0; r < 4; ++r) {
    const int row = mt * 16 + g * 4 + r;
    outp[(long)row * 512 + col] = acc[r] + addp[(long)row * 512 + col];
  }
}

// ---- kernels --------------------------------------------------------------

// Split two fp32 512x512 matrices into 3 bf16 terms (MFMA B-fragment order).
__global__ __launch_bounds__(512) void k_split2(const float* __restrict__ m0,
                                                const float* __restrict__ m1,
                                                __bf16* __restrict__ f0,
                                                __bf16* __restrict__ f1) {
  const int bb = blockIdx.x;
  const float* m = (bb < 512) ? m0 : m1;
  __bf16* f = (bb < 512) ? f0 : f1;
  const int idx = (bb & 511) * 512 + threadIdx.x;
  const int j = idx & 7, l = (idx >> 3) & 63, kk = (idx >> 9) & 15, nt = idx >> 13;
  const int k = kk * 32 + (l >> 4) * 8 + j;
  const int n = nt * 16 + (l & 15);
  const float v = m[k * 512 + n];
  const __bf16 t1 = (__bf16)v;
  const float r1 = v - (float)t1;
  const __bf16 t2 = (__bf16)r1;
  f[idx] = t1;
  f[TS + idx] = t2;
  f[2 * TS + idx] = (__bf16)(r1 - (float)t2);
}

// xW remainder kernel (base = first M=64 tile index).
__global__ __launch_bounds__(512) void k_xw(const float* __restrict__ x,
                                            const __bf16* __restrict__ wf,
                                            float* __restrict__ out, int base) {
  __shared__ __align__(16) char smem[64 * PP * 2];
  xw_dev(base + blockIdx.x, x, wf, out, smem);
}

// Co-dispatch: blocks 0-127 advance squaring chain; blocks 128+ do xw tiles.
__global__ __launch_bounds__(512) void k_xwsq(const float* __restrict__ sqa,
                                              const __bf16* __restrict__ sqbf,
                                              float* __restrict__ sqo32,
                                              __bf16* __restrict__ sqofr,
                                              const float* __restrict__ x,
                                              const __bf16* __restrict__ wf,
                                              float* __restrict__ out, int base) {
  __shared__ __align__(16) char smem[64 * PP * 2];
  const int b = blockIdx.x;
  if (b < 128)
    sq_dev(b, sqa, sqbf, sqo32, sqofr, (float*)smem);
  else
    xw_dev(base + (b - 128), x, wf, out, smem);
}

// Co-dispatch: b<128 sq; (pwEn && b<256) power task; else tree up-stage.
__global__ __launch_bounds__(512) void k_combo(const float* __restrict__ sqa,
                                               const __bf16* __restrict__ sqbf,
                                               float* __restrict__ sqo32,
                                               __bf16* __restrict__ sqofr,
                                               const float* __restrict__ pwa,
                                               const __bf16* __restrict__ pwbf,
                                               float* __restrict__ pwo32,
                                               __bf16* __restrict__ pwofr,
                                               const float* __restrict__ prin,
                                               const __bf16* __restrict__ prbf,
                                               float* __restrict__ prout,
                                               int pwEn) {
  __shared__ float hbuf[ST32];
  const int b = blockIdx.x;
  if (b < 128)
    sq_dev(b, sqa, sqbf, sqo32, sqofr, hbuf);
  else if (pwEn && b < 256)
    sq_dev(b - 128, pwa, pwbf, pwo32, pwofr, hbuf);
  else
    pair_dev(b - (pwEn ? 256 : 128), prin, prbf, prout);
}

// Level-0 up-sweep (R8-proven) + y materialization at j in {1,3,5,7}.
__global__ __launch_bounds__(1024) void k_local(float* out,
                                                const __bf16* __restrict__ rf,
                                                const __bf16* __restrict__ r2f,
                                                float* __restrict__ sout) {
  __shared__ __bf16 Phi[32 * PP], Plo[32 * PP], Qhi[32 * PP], Qlo[32 * PP];
  const long c = blockIdx.x;
  stage32p(out + c * 8 * UDIM, TDIM * UDIM, Phi, Plo);  // y_0 = xw
  __syncthreads();
  pstep32<2, 3, true>(Phi, Plo, rf, out, c * 8 + 1);
  write_bt(Phi, Plo, out, c * 8 + 1);                   // y_1
  dstep(Phi, Plo, Qhi, Qlo, r2f, rf, out, c * 8 + 2, c * 8 + 3);
  write_bt(Phi, Plo, out, c * 8 + 3);                   // y_3
  dstep(Phi, Plo, Qhi, Qlo, r2f, rf, out, c * 8 + 4, c * 8 + 5);
  write_bt(Phi, Plo, out, c * 8 + 5);                   // y_5
  dstep(Phi, Plo, Qhi, Qlo, r2f, rf, out, c * 8 + 6, c * 8 + 7);
  write_bt(Phi, Plo, out, c * 8 + 7);                   // y_7
  write_flat(Phi, Plo, sout + c * ST32);                // S[c]
}

// Parallel fix, j in {0,1,3,5,7}: out[8c+j] += E0[c] @ R^(j+1).
// Grid 640 = 128 chunk-pairs x 5 slots.
__global__ __launch_bounds__(1024) void k_add5(const float* __restrict__ e0,
                                               float* out,
                                               const __bf16* __restrict__ F) {
  __shared__ __bf16 Phi[64 * PP], Plo[64 * PP];
  const int b = blockIdx.x, pi = b / 5, s = b % 5;
  const int jv[5] = {0, 1, 3, 5, 7};
  const int fv[5] = {0, 1, 2, 11, 3};   // R^1,R^2,R^4,R^6,R^8
  const int j = jv[s];
  stage64c(e0 + (long)pi * 2 * ST32, Phi, Plo);
  __syncthreads();
  mul_rmw64(Phi, Plo, F + (long)fv[s] * FE, out,
            (2L * pi) * 8 + j, (2L * pi + 1) * 8 + j);
}

// Parallel odd fill, j in {2,4,6}: out[t] += h_{t-1} @ R (h_{t-1} final).
// Grid 384 = 128 chunk-pairs x 3 slots.
__global__ __launch_bounds__(1024) void k_odd(float* out,
                                              const __bf16* __restrict__ F) {
  __shared__ __bf16 Phi[64 * PP], Plo[64 * PP];
  const int b = blockIdx.x, pi = b / 3, s = b % 3;
  const int j = 2 + 2 * s;
  const long tA = (2L * pi) * 8 + j, tB = (2L * pi + 1) * 8 + j;
  stage_bt64(out, tA - 1, tB - 1, Phi, Plo);
  __syncthreads();
  mul_rmw64(Phi, Plo, F, out, tA, tB);
}

// Tree down-stage (in place into child-level buffer):
//   ulev[2p+1] = epar[p] @ M + ulev[2p];  ulev[2p] = epar[p]
__global__ __launch_bounds__(512) void k_down(const float* __restrict__ epar,
                                              float* __restrict__ ulev,
                                              const __bf16* __restrict__ bf) {
  const int p = blockIdx.x >> 3, cs = blockIdx.x & 7;
  const int tid = threadIdx.x, l = tid & 63, w = tid >> 6, g = l >> 4, li = l & 15;
  const int mt = w >> 2, ntg = cs * 4 + (w & 3);
  const f32x4 acc = one_mm<2, 3>(epar + (long)p * ST32, bf, mt, ntg);
  float* evp = ulev + (long)(2 * p) * ST32;
  float* outp = ulev + (long)(2 * p + 1) * ST32;
  const int col = ntg * 16 + li;
  float cp[4];
#pragma unroll
  for (int r = 0; r < 4; ++r) {
    const int row = mt * 16 + g * 4 + r;
    const long off = (long)row * 512 + col;
    cp[r] = epar[(long)p * ST32 + off];
    outp[off] = acc[r] + evp[off];
  }
  __syncthreads();
#pragma unroll
  for (int r = 0; r < 4; ++r) {
    const int row = mt * 16 + g * 4 + r;
    evp[(long)row * 512 + col] = cp[r];
  }
}

extern "C" void kernel_launch(void* const* d_in, const int* in_sizes, int n_in,
                              void* d_out, int out_size, void* d_ws, size_t ws_size,
                              hipStream_t stream) {
  (void)in_sizes; (void)n_in; (void)out_size; (void)ws_size;
  const float* x  = (const float*)d_in[0];
  const float* W  = (const float*)d_in[1];
  const float* R  = (const float*)d_in[2];
  const float* h0 = (const float*)d_in[3];
  float* out = (float*)d_out;

  // F[0..10] = frags of R^(2^i); F[11] = frags of R^6.
  __bf16* F  = (__bf16*)d_ws;
  __bf16* Fw = F + 12 * FE;            // frags of W
  float* PA = (float*)(Fw + FE);
  float* PB = PA + TS;
  float* PC = PB + TS;
  float* PD = PC + TS;                 // dummy fp32 out for R^6 task
  float* Sbuf = PD + TS;               // 256 chunk sums -> entries E0
  float* Ub[8];
  {
    float* up = Sbuf + 256 * ST32;
    for (int k = 1; k <= 7; ++k) { Ub[k] = up; up += (1L << (8 - k)) * ST32; }
  }

  k_split2<<<1024, 512, 0, stream>>>(W, R, Fw, F);

  // Head squarings co-dispatched with xw slices:
  //   F[1]=R^2->PA ; F[2]=R^4->PB ; F[3]=R^8->PC
  k_xwsq<<<384, 512, 0, stream>>>(R, F, PA, F + FE, x, Fw, out, 0);
  k_xwsq<<<384, 512, 0, stream>>>(PA, F + FE, PB, F + 2L * FE, x, Fw, out, 256);
  k_xwsq<<<384, 512, 0, stream>>>(PB, F + 2L * FE, PC, F + 3L * FE, x, Fw, out, 512);
  k_xw<<<256, 512, 0, stream>>>(x, Fw, out, 768);

  k_local<<<256, 1024, 0, stream>>>(out, F, F + FE, Sbuf);

  // phases k=1..7: sq chain F[k+3] | (k=1: R^6 = R^4 @ R^2frags) | tree-up k
  for (int k = 1; k <= 7; ++k) {
    const int i = k + 3;
    const float* sqa = (k == 1) ? PC : ((k & 1) ? PB : PA);
    float* sqo = (k & 1) ? PA : PB;
    const float* prin = (k == 1) ? Sbuf : Ub[k - 1];
    const int npr = (1 << (8 - k)) * 8;
    const int pwEn = (k == 1) ? 1 : 0;
    k_combo<<<128 + (pwEn ? 128 : 0) + npr, 512, 0, stream>>>(
        sqa, F + (long)(i - 1) * FE, sqo, F + (long)i * FE,
        PB, F + FE, PD, F + 11L * FE,
        prin, F + (long)(k + 2) * FE, Ub[k], pwEn);
  }

  // down-sweep: entries, in place into each child level (E0 lands in Sbuf)
  k_down<<<8, 512, 0, stream>>>(h0, Ub[7], F + 10L * FE);
  for (int k = 7; k >= 1; --k) {
    float* ul = (k == 1) ? Sbuf : Ub[k - 1];
    k_down<<<(1 << (8 - k)) * 8, 512, 0, stream>>>(Ub[k], ul, F + (long)(k + 2) * FE);
  }

  // parallel fix: even/odd decomposition
  k_add5<<<640, 1024, 0, stream>>>(Sbuf, out, F);
  k_odd<<<384, 1024, 0, stream>>>(out, F);
}

// Round 13
// 520.988 us; speedup vs baseline: 1.3089x; 1.2460x over previous
//
#include <hip/hip_runtime.h>
#include <hip/hip_bf16.h>

// Linear recurrence h_t = x_t@W + h_{t-1}@R, parallel scan, chunk C=8.
// R13 = R8 skeleton (607us) + LDS A-staging in tree up/down tasks
// (sq_dev's proven swizzled-stage pattern) to kill the 4x per-wave
// duplication of A-state reads from L2. Everything else byte-frozen.
// Per-CU L2-ingest model (~58 GB/s/CU): local & fix0 at their traffic
// floors; tree was 2x above floor due to A-dup.

typedef float f32x4 __attribute__((ext_vector_type(4)));
typedef __bf16 bf16x8 __attribute__((ext_vector_type(8)));

#define TDIM 2048L
#define UDIM 512L
#define ST32 16384L     // elems per [32,512] state
#define ST64 32768L     // elems per [64,512] tile
#define TS 262144L      // elems per frag term
#define FE 786432L      // elems per 3-term frag matrix
#define PP 520          // padded plane row stride (bf16 elems)

__device__ __forceinline__ f32x4 mfma16(bf16x8 a, bf16x8 b, f32x4 c) {
  return __builtin_amdgcn_mfma_f32_16x16x32_bf16(a, b, c, 0, 0, 0);
}

// fp32 [32][512] swizzle (staging for sq/pair/down)
__device__ __forceinline__ int hidx(int row, int col) {
  return row * 512 + (col ^ ((row & 7) << 3));
}

__device__ __forceinline__ void pack8(const f32x4& v0, const f32x4& v1,
                                      bf16x8& hv, bf16x8& lv) {
#pragma unroll
  for (int j = 0; j < 4; ++j) {
    const float a = v0[j];
    const __bf16 ha = (__bf16)a;
    hv[j] = ha; lv[j] = (__bf16)(a - (float)ha);
    const float b = v1[j];
    const __bf16 hb = (__bf16)b;
    hv[j + 4] = hb; lv[j + 4] = (__bf16)(b - (float)hb);
  }
}

// ---- M=32 pair-plane helpers (stride PP, blockDim-stride loops) -----------

__device__ __forceinline__ void stage32p(const float* __restrict__ src,
                                         long pitch, __bf16* Phi, __bf16* Plo) {
  for (int i = threadIdx.x; i < 2048; i += blockDim.x) {
    const int row = i >> 6, cb = i & 63;
    const float* p = src + (long)row * pitch + cb * 8;
    bf16x8 hv, lv;
    pack8(*(const f32x4*)p, *(const f32x4*)(p + 4), hv, lv);
    const int o = row * PP + cb * 8;
    *(bf16x8*)(Phi + o) = hv;
    *(bf16x8*)(Plo + o) = lv;
  }
}

__device__ __forceinline__ void write_bt(const __bf16* Phi, const __bf16* Plo,
                                         float* out, long t) {
  for (int i = threadIdx.x; i < 2048; i += blockDim.x) {
    const int row = i >> 6, cb = i & 63;
    const int o = row * PP + cb * 8;
    const bf16x8 hv = *(const bf16x8*)(Phi + o);
    const bf16x8 lv = *(const bf16x8*)(Plo + o);
    f32x4 o0, o1;
#pragma unroll
    for (int j = 0; j < 4; ++j) {
      o0[j] = (float)hv[j] + (float)lv[j];
      o1[j] = (float)hv[j + 4] + (float)lv[j + 4];
    }
    float* dst = out + (long)row * (TDIM * UDIM) + t * UDIM + cb * 8;
    *(f32x4*)dst = o0;
    *(f32x4*)(dst + 4) = o1;
  }
}

__device__ __forceinline__ void write_flat(const __bf16* Phi, const __bf16* Plo,
                                           float* dst) {
  for (int i = threadIdx.x; i < 2048; i += blockDim.x) {
    const int row = i >> 6, cb = i & 63;
    const int o = row * PP + cb * 8;
    const bf16x8 hv = *(const bf16x8*)(Phi + o);
    const bf16x8 lv = *(const bf16x8*)(Plo + o);
    f32x4 o0, o1;
#pragma unroll
    for (int j = 0; j < 4; ++j) {
      o0[j] = (float)hv[j] + (float)lv[j];
      o1[j] = (float)hv[j + 4] + (float)lv[j + 4];
    }
    float* d = dst + row * 512 + cb * 8;
    *(f32x4*)d = o0;
    *(f32x4*)(d + 4) = o1;
  }
}

// One step on M=32 planes (1024 thr, 16 waves, wave owns 2 nt)
template <int NTERM, int NPROD, bool HAS_H>
__device__ __forceinline__ void pstep32(__bf16* Phi, __bf16* Plo,
                                        const __bf16* __restrict__ bfrag,
                                        const float* __restrict__ xwbase, long t) {
  const int tid = threadIdx.x, l = tid & 63, w = tid >> 6, g = l >> 4, li = l & 15;
  f32x4 addv[2][2];
#pragma unroll
  for (int mt = 0; mt < 2; ++mt)
#pragma unroll
    for (int q = 0; q < 2; ++q) {
      const int col = (w * 2 + q) * 16 + li;
#pragma unroll
      for (int r = 0; r < 4; ++r) {
        const int bat = mt * 16 + g * 4 + r;
        addv[mt][q][r] = xwbase[(long)bat * (TDIM * UDIM) + t * UDIM + col];
      }
    }

  f32x4 acc[2][2] = {};
  if (HAS_H) {
#pragma unroll 2
    for (int kk = 0; kk < 16; ++kk) {
      bf16x8 b[NTERM][2];
#pragma unroll
      for (int q = 0; q < 2; ++q) {
        const long fo = (((long)(w * 2 + q) * 16 + kk) * 64 + l) * 8;
#pragma unroll
        for (int tt = 0; tt < NTERM; ++tt)
          b[tt][q] = *(const bf16x8*)(bfrag + (long)tt * TS + fo);
      }
#pragma unroll
      for (int mt = 0; mt < 2; ++mt) {
        const int o = (mt * 16 + li) * PP + kk * 32 + g * 8;
        const bf16x8 a1 = *(const bf16x8*)(Phi + o);
        const bf16x8 a2 = *(const bf16x8*)(Plo + o);
#pragma unroll
        for (int q = 0; q < 2; ++q) {
          acc[mt][q] = mfma16(a1, b[0][q], acc[mt][q]);
          acc[mt][q] = mfma16(a1, b[1][q], acc[mt][q]);
          if (NPROD >= 3) acc[mt][q] = mfma16(a2, b[0][q], acc[mt][q]);
          if (NPROD >= 4) acc[mt][q] = mfma16(a1, b[NTERM - 1][q], acc[mt][q]);
        }
      }
    }
    __syncthreads();  // plane reads done before overwrite
  }

#pragma unroll
  for (int mt = 0; mt < 2; ++mt)
#pragma unroll
    for (int q = 0; q < 2; ++q) {
      const int col = (w * 2 + q) * 16 + li;
#pragma unroll
      for (int r = 0; r < 4; ++r) {
        const float v = (HAS_H ? acc[mt][q][r] : 0.0f) + addv[mt][q][r];
        const int row = mt * 16 + g * 4 + r;
        const __bf16 hi = (__bf16)v;
        const int o = row * PP + col;
        Phi[o] = hi;
        Plo[o] = (__bf16)(v - (float)hi);
      }
    }
  __syncthreads();
}

// Double step: h <- h@R^2 + xw[t1]@R + xw[t2]  (k_local, 1024 thr)
__device__ __forceinline__ void dstep(__bf16* Phi, __bf16* Plo,
                                      __bf16* Qhi, __bf16* Qlo,
                                      const __bf16* __restrict__ r2f,
                                      const __bf16* __restrict__ rf,
                                      const float* __restrict__ xw,
                                      long t1, long t2) {
  stage32p(xw + t1 * UDIM, TDIM * UDIM, Qhi, Qlo);
  __syncthreads();
  const int tid = threadIdx.x, l = tid & 63, w = tid >> 6, g = l >> 4, li = l & 15;
  f32x4 addv[2][2];
#pragma unroll
  for (int mt = 0; mt < 2; ++mt)
#pragma unroll
    for (int q = 0; q < 2; ++q) {
      const int col = (w * 2 + q) * 16 + li;
#pragma unroll
      for (int r = 0; r < 4; ++r) {
        const int bat = mt * 16 + g * 4 + r;
        addv[mt][q][r] = xw[(long)bat * (TDIM * UDIM) + t2 * UDIM + col];
      }
    }
  f32x4 acc[2][2] = {};
#pragma unroll 2
  for (int kk = 0; kk < 16; ++kk) {
    bf16x8 c0[2], c1[2], d0[2], d1[2];
#pragma unroll
    for (int q = 0; q < 2; ++q) {
      const long fo = (((long)(w * 2 + q) * 16 + kk) * 64 + l) * 8;
      c0[q] = *(const bf16x8*)(r2f + fo);
      c1[q] = *(const bf16x8*)(r2f + TS + fo);
      d0[q] = *(const bf16x8*)(rf + fo);
      d1[q] = *(const bf16x8*)(rf + TS + fo);
    }
#pragma unroll
    for (int mt = 0; mt < 2; ++mt) {
      const int o = (mt * 16 + li) * PP + kk * 32 + g * 8;
      const bf16x8 h1 = *(const bf16x8*)(Phi + o);
      const bf16x8 h2 = *(const bf16x8*)(Plo + o);
      const bf16x8 q1 = *(const bf16x8*)(Qhi + o);
      const bf16x8 q2 = *(const bf16x8*)(Qlo + o);
#pragma unroll
      for (int q = 0; q < 2; ++q) {
        acc[mt][q] = mfma16(h1, c0[q], acc[mt][q]);
        acc[mt][q] = mfma16(q1, d0[q], acc[mt][q]);
        acc[mt][q] = mfma16(h1, c1[q], acc[mt][q]);
        acc[mt][q] = mfma16(q1, d1[q], acc[mt][q]);
        acc[mt][q] = mfma16(h2, c0[q], acc[mt][q]);
        acc[mt][q] = mfma16(q2, d0[q], acc[mt][q]);
      }
    }
  }
  __syncthreads();
#pragma unroll
  for (int mt = 0; mt < 2; ++mt)
#pragma unroll
    for (int q = 0; q < 2; ++q) {
      const int col = (w * 2 + q) * 16 + li;
#pragma unroll
      for (int r = 0; r < 4; ++r) {
        const float v = acc[mt][q][r] + addv[mt][q][r];
        const int row = mt * 16 + g * 4 + r;
        const __bf16 hi = (__bf16)v;
        const int o = row * PP + col;
        Phi[o] = hi;
        Plo[o] = (__bf16)(v - (float)hi);
      }
    }
  __syncthreads();
}

// ---- device tasks ----------------------------------------------------------

// xW task, M=64: 512 thr = 8 waves; wave owns 4 nt; mt=0..3. 2 products.
__device__ __forceinline__ void xw_dev(long blk, const float* __restrict__ x,
                                       const __bf16* __restrict__ wf,
                                       float* __restrict__ out, char* smem) {
  __bf16* Phi = (__bf16*)smem;  // [64][PP] hi-only = 66560 B
  const float* src = x + blk * ST64;
  for (int i = threadIdx.x; i < 4096; i += 512) {
    const int row = i >> 6, cb = i & 63;
    const f32x4 v0 = *(const f32x4*)(src + (long)row * 512 + cb * 8);
    const f32x4 v1 = *(const f32x4*)(src + (long)row * 512 + cb * 8 + 4);
    bf16x8 hv;
#pragma unroll
    for (int j = 0; j < 4; ++j) {
      hv[j] = (__bf16)v0[j];
      hv[j + 4] = (__bf16)v1[j];
    }
    *(bf16x8*)(Phi + row * PP + cb * 8) = hv;
  }
  __syncthreads();
  const int tid = threadIdx.x, l = tid & 63, w = tid >> 6, g = l >> 4, li = l & 15;
  f32x4 acc[4][4] = {};
#pragma unroll 2
  for (int kk = 0; kk < 16; ++kk) {
    bf16x8 b0[4], b1[4];
#pragma unroll
    for (int q = 0; q < 4; ++q) {
      const long fo = (((long)(w * 4 + q) * 16 + kk) * 64 + l) * 8;
      b0[q] = *(const bf16x8*)(wf + fo);
      b1[q] = *(const bf16x8*)(wf + TS + fo);
    }
#pragma unroll
    for (int mt = 0; mt < 4; ++mt) {
      const bf16x8 a1 = *(const bf16x8*)(Phi + (mt * 16 + li) * PP + kk * 32 + g * 8);
#pragma unroll
      for (int q = 0; q < 4; ++q) {
        acc[mt][q] = mfma16(a1, b0[q], acc[mt][q]);
        acc[mt][q] = mfma16(a1, b1[q], acc[mt][q]);
      }
    }
  }
  float* gdst = out + blk * ST64;
#pragma unroll
  for (int mt = 0; mt < 4; ++mt)
#pragma unroll
    for (int q = 0; q < 4; ++q) {
      const int col = (w * 4 + q) * 16 + li;
#pragma unroll
      for (int r = 0; r < 4; ++r)
        gdst[(long)(mt * 16 + g * 4 + r) * 512 + col] = acc[mt][q][r];
    }
}

// Stage a [32,512] fp32 state into swizzled LDS (512 thr).
__device__ __forceinline__ void stage_sw(const float* __restrict__ src,
                                         float* hbuf) {
  for (int i = threadIdx.x; i < 4096; i += 512) {
    const int flat = i * 4, row = flat >> 9, col = flat & 511;
    *(f32x4*)&hbuf[hidx(row, col)] = *(const f32x4*)&src[flat];
  }
}

// A @ Bfrag with A in swizzled LDS (2-term, 3 products).
__device__ __forceinline__ f32x4 lds_mm(const float* hbuf,
                                        const __bf16* __restrict__ bf,
                                        int mt, int ntg) {
  const int tid = threadIdx.x, l = tid & 63, g = (l >> 4) & 3, li = l & 15;
  f32x4 acc = {};
#pragma unroll 2
  for (int kk = 0; kk < 16; ++kk) {
    const long fo = (((long)ntg * 16 + kk) * 64 + l) * 8;
    const bf16x8 b0 = *(const bf16x8*)(bf + fo);
    const bf16x8 b1 = *(const bf16x8*)(bf + TS + fo);
    bf16x8 a1, a2;
    const float* pp = &hbuf[hidx(mt * 16 + li, kk * 32 + g * 8)];
#pragma unroll
    for (int j = 0; j < 8; ++j) {
      const float v = pp[j];
      const __bf16 hi = (__bf16)v;
      a1[j] = hi;
      a2[j] = (__bf16)(v - (float)hi);
    }
    acc = mfma16(a1, b0, acc);
    acc = mfma16(a1, b1, acc);
    acc = mfma16(a2, b0, acc);
  }
  return acc;
}

// Multiply task (128 blocks x 512 thr): out = A @ Bfrag, fp32 + frag split.
__device__ __forceinline__ void sq_dev(int b, const float* __restrict__ a,
                                       const __bf16* __restrict__ bf,
                                       float* __restrict__ of32,
                                       __bf16* __restrict__ ofr, float* hbuf) {
  const int rg = b >> 3, cg = b & 7;
  const int tid = threadIdx.x, l = tid & 63, w = tid >> 6, g = l >> 4, li = l & 15;
  stage_sw(a + (long)rg * ST32, hbuf);
  __syncthreads();
  const int mt = w >> 2, q = w & 3, ntg = cg * 4 + q;
  f32x4 acc = {};
#pragma unroll 2
  for (int kk = 0; kk < 16; ++kk) {
    const long fo = (((long)ntg * 16 + kk) * 64 + l) * 8;
    const bf16x8 b0 = *(const bf16x8*)(bf + fo);
    const bf16x8 b1 = *(const bf16x8*)(bf + TS + fo);
    const bf16x8 b2 = *(const bf16x8*)(bf + 2 * TS + fo);
    bf16x8 a1, a2;
    const float* pp = &hbuf[hidx(mt * 16 + li, kk * 32 + g * 8)];
#pragma unroll
    for (int j = 0; j < 8; ++j) {
      const float v = pp[j];
      const __bf16 hi = (__bf16)v;
      a1[j] = hi;
      a2[j] = (__bf16)(v - (float)hi);
    }
    acc = mfma16(a1, b0, acc);
    acc = mfma16(a1, b1, acc);
    acc = mfma16(a2, b0, acc);
    acc = mfma16(a1, b2, acc);
  }
  const int n = ntg * 16 + li;
#pragma unroll
  for (int r = 0; r < 4; ++r) {
    const int k = rg * 32 + mt * 16 + g * 4 + r;
    const float v = acc[r];
    of32[(long)k * 512 + n] = v;
    const __bf16 t1 = (__bf16)v;
    const float r1 = v - (float)t1;
    const __bf16 t2 = (__bf16)r1;
    const long fi = (((long)(n >> 4) * 16 + (k >> 5)) * 64 + ((k >> 3) & 3) * 16 + (n & 15)) * 8 + (k & 7);
    ofr[fi] = t1;
    ofr[TS + fi] = t2;
    ofr[2 * TS + fi] = (__bf16)(r1 - (float)t2);
  }
}

// Tree up-stage task (LDS-staged A): out[p] = in[2p] @ M + in[2p+1].
__device__ __forceinline__ void pair_dev(int b, const float* __restrict__ in,
                                         const __bf16* __restrict__ bf,
                                         float* __restrict__ outb, float* hbuf) {
  const int p = b >> 3, cs = b & 7;
  const int tid = threadIdx.x, l = tid & 63, w = tid >> 6, g = l >> 4, li = l & 15;
  stage_sw(in + (long)(2 * p) * ST32, hbuf);
  __syncthreads();
  const int mt = w >> 2, ntg = cs * 4 + (w & 3);
  const f32x4 acc = lds_mm(hbuf, bf, mt, ntg);
  const float* addp = in + (long)(2 * p + 1) * ST32;
  float* outp = outb + (long)p * ST32;
  const int col = ntg * 16 + li;
#pragma unroll
  for (int r = 0; r < 4; ++r) {
    const int row = mt * 16 + g * 4 + r;
    outp[(long)row * 512 + col] = acc[r] + addp[(long)row * 512 + col];
  }
}

// ---- kernels --------------------------------------------------------------

// Split two fp32 512x512 matrices into 3 bf16 terms (MFMA B-fragment order).
__global__ __launch_bounds__(512) void k_split2(const float* __restrict__ m0,
                                                const float* __restrict__ m1,
                                                __bf16* __restrict__ f0,
                                                __bf16* __restrict__ f1) {
  const int bb = blockIdx.x;
  const float* m = (bb < 512) ? m0 : m1;
  __bf16* f = (bb < 512) ? f0 : f1;
  const int idx = (bb & 511) * 512 + threadIdx.x;
  const int j = idx & 7, l = (idx >> 3) & 63, kk = (idx >> 9) & 15, nt = idx >> 13;
  const int k = kk * 32 + (l >> 4) * 8 + j;
  const int n = nt * 16 + (l & 15);
  const float v = m[k * 512 + n];
  const __bf16 t1 = (__bf16)v;
  const float r1 = v - (float)t1;
  const __bf16 t2 = (__bf16)r1;
  f[idx] = t1;
  f[TS + idx] = t2;
  f[2 * TS + idx] = (__bf16)(r1 - (float)t2);
}

// xW remainder kernel (base = first M=64 tile index).
__global__ __launch_bounds__(512) void k_xw(const float* __restrict__ x,
                                            const __bf16* __restrict__ wf,
                                            float* __restrict__ out, int base) {
  __shared__ __align__(16) char smem[64 * PP * 2];
  xw_dev(base + blockIdx.x, x, wf, out, smem);
}

// Co-dispatch: blocks 0-127 advance squaring chain; blocks 128+ do xw tiles.
__global__ __launch_bounds__(512) void k_xwsq(const float* __restrict__ sqa,
                                              const __bf16* __restrict__ sqbf,
                                              float* __restrict__ sqo32,
                                              __bf16* __restrict__ sqofr,
                                              const float* __restrict__ x,
                                              const __bf16* __restrict__ wf,
                                              float* __restrict__ out, int base) {
  __shared__ __align__(16) char smem[64 * PP * 2];
  const int b = blockIdx.x;
  if (b < 128)
    sq_dev(b, sqa, sqbf, sqo32, sqofr, (float*)smem);
  else
    xw_dev(base + (b - 128), x, wf, out, smem);
}

// Co-dispatch: blocks 0-127 squaring; blocks 128+ tree up-stage.
__global__ __launch_bounds__(512) void k_combo(const float* __restrict__ sqa,
                                               const __bf16* __restrict__ sqbf,
                                               float* __restrict__ sqo32,
                                               __bf16* __restrict__ sqofr,
                                               const float* __restrict__ prin,
                                               const __bf16* __restrict__ prbf,
                                               float* __restrict__ prout) {
  __shared__ float hbuf[ST32];
  const int b = blockIdx.x;
  if (b < 128)
    sq_dev(b, sqa, sqbf, sqo32, sqofr, hbuf);
  else
    pair_dev(b - 128, prin, prbf, prout, hbuf);
}

// Level-0 up-sweep: h = xw[t0]; 1 single step; 3 double steps. 2-term R.
__global__ __launch_bounds__(1024) void k_local(const float* __restrict__ xw,
                                                const __bf16* __restrict__ rf,
                                                const __bf16* __restrict__ r2f,
                                                float* __restrict__ sout) {
  __shared__ __bf16 Phi[32 * PP], Plo[32 * PP], Qhi[32 * PP], Qlo[32 * PP];
  const long c = blockIdx.x;
  stage32p(xw + c * 8 * UDIM, TDIM * UDIM, Phi, Plo);  // h = xw[t0]
  __syncthreads();
  pstep32<2, 3, true>(Phi, Plo, rf, xw, c * 8 + 1);
  dstep(Phi, Plo, Qhi, Qlo, r2f, rf, xw, c * 8 + 2, c * 8 + 3);
  dstep(Phi, Plo, Qhi, Qlo, r2f, rf, xw, c * 8 + 4, c * 8 + 5);
  dstep(Phi, Plo, Qhi, Qlo, r2f, rf, xw, c * 8 + 6, c * 8 + 7);
  write_flat(Phi, Plo, sout + c * ST32);
}

// Final pass: 8 serial steps from corrected entry; intermediates ARE outputs.
__global__ __launch_bounds__(1024) void k_fix0(const float* __restrict__ e0,
                                               float* out,
                                               const __bf16* __restrict__ rf) {
  __shared__ __bf16 Phi[32 * PP], Plo[32 * PP];
  const long c = blockIdx.x;
  stage32p(e0 + c * ST32, 512, Phi, Plo);
  __syncthreads();
  for (int j = 0; j < 8; ++j) {
    pstep32<2, 3, true>(Phi, Plo, rf, out, c * 8 + j);
    write_bt(Phi, Plo, out, c * 8 + j);
  }
}

// Tree down-stage (LDS-staged parent), in place into child-level buffer:
//   ulev[2p+1] = epar[p] @ M + ulev[2p];  ulev[2p] = epar[p]
__global__ __launch_bounds__(512) void k_down(const float* __restrict__ epar,
                                              float* __restrict__ ulev,
                                              const __bf16* __restrict__ bf) {
  __shared__ float hbuf[ST32];
  const int p = blockIdx.x >> 3, cs = blockIdx.x & 7;
  const int tid = threadIdx.x, l = tid & 63, w = tid >> 6, g = l >> 4, li = l & 15;
  stage_sw(epar + (long)p * ST32, hbuf);
  __syncthreads();
  const int mt = w >> 2, ntg = cs * 4 + (w & 3);
  const f32x4 acc = lds_mm(hbuf, bf, mt, ntg);
  float* evp = ulev + (long)(2 * p) * ST32;
  float* outp = ulev + (long)(2 * p + 1) * ST32;
  const int col = ntg * 16 + li;
  float cp[4];
#pragma unroll
  for (int r = 0; r < 4; ++r) {
    const int row = mt * 16 + g * 4 + r;
    const long off = (long)row * 512 + col;
    cp[r] = hbuf[hidx(row, col)];     // = epar[p][row][col], exact
    outp[off] = acc[r] + evp[off];
  }
  __syncthreads();
#pragma unroll
  for (int r = 0; r < 4; ++r) {
    const int row = mt * 16 + g * 4 + r;
    evp[(long)row * 512 + col] = cp[r];
  }
}

extern "C" void kernel_launch(void* const* d_in, const int* in_sizes, int n_in,
                              void* d_out, int out_size, void* d_ws, size_t ws_size,
                              hipStream_t stream) {
  (void)in_sizes; (void)n_in; (void)out_size; (void)ws_size;
  const float* x  = (const float*)d_in[0];
  const float* W  = (const float*)d_in[1];
  const float* R  = (const float*)d_in[2];
  const float* h0 = (const float*)d_in[3];
  float* out = (float*)d_out;

  __bf16* F  = (__bf16*)d_ws;          // F[i] = frags of R^(2^i), i=0..10
  __bf16* Fw = F + 11 * FE;            // frags of W
  float* P1 = (float*)(Fw + FE);
  float* P2 = P1 + TS;
  float* Sbuf = P2 + TS;               // 256 chunk sums -> entries E0
  float* Ub[8];
  {
    float* up = Sbuf + 256 * ST32;
    for (int k = 1; k <= 7; ++k) { Ub[k] = up; up += (1L << (8 - k)) * ST32; }
  }

  k_split2<<<1024, 512, 0, stream>>>(W, R, Fw, F);

  // Head squarings co-dispatched with xw slices (256 M=64 tiles each):
  //   F[1]=R^2 ; F[2]=R^4 ; F[3]=R^8  (fp32 ping-pong, frag split fused)
  k_xwsq<<<384, 512, 0, stream>>>(R, F, P1, F + FE, x, Fw, out, 0);
  k_xwsq<<<384, 512, 0, stream>>>(P1, F + FE, P2, F + 2L * FE, x, Fw, out, 256);
  k_xwsq<<<384, 512, 0, stream>>>(P2, F + 2L * FE, P1, F + 3L * FE, x, Fw, out, 512);
  k_xw<<<256, 512, 0, stream>>>(x, Fw, out, 768);

  k_local<<<256, 1024, 0, stream>>>(out, F, F + FE, Sbuf);

  // phases k=1..7: sq (F[k+3] <- F[k+2], fp32 ping-pong) || tree-up stage k
  for (int k = 1; k <= 7; ++k) {
    const int i = k + 3;  // chain index being produced
    const float* sqa = (i & 1) ? P2 : P1;   // fp32 of R^(2^(i-1))
    float* sqo = (i & 1) ? P1 : P2;
    const float* prin = (k == 1) ? Sbuf : Ub[k - 1];
    const int npr = (1 << (8 - k)) * 8;
    k_combo<<<128 + npr, 512, 0, stream>>>(sqa, F + (long)(i - 1) * FE, sqo,
                                           F + (long)i * FE, prin,
                                           F + (long)(k + 2) * FE, Ub[k]);
  }

  // down-sweep: entries, in place into each child level (E0 lands in Sbuf)
  k_down<<<8, 512, 0, stream>>>(h0, Ub[7], F + 10L * FE);
  for (int k = 7; k >= 1; --k) {
    float* ul = (k == 1) ? Sbuf : Ub[k - 1];
    k_down<<<(1 << (8 - k)) * 8, 512, 0, stream>>>(Ub[k], ul, F + (long)(k + 2) * FE);
  }

  k_fix0<<<256, 1024, 0, stream>>>(Sbuf, out, F);
}

// Round 14
// 488.681 us; speedup vs baseline: 1.3954x; 1.0661x over previous
//
#include <hip/hip_runtime.h>
#include <hip/hip_bf16.h>

// Linear recurrence h_t = x_t@W + h_{t-1}@R, parallel scan, chunk C=8.
// R14 = R13 (521us) + three cuts:
//  1) xw: W 1-term / 1 product (x already bf16-hi; ~0.3% rel on h, safe)
//  2) down-k=1 fused into fix0 (odd chunks: entry = E1@R^8 + S[2p])
//  3) pstep32 kk-loop unroll 4 (deeper frag-load ILP)
// Per-CU-ingest model (~60 GB/s per 16 waves) validated R9-R13:
// fix0/local at their 2-term frag floors; xw/mid were above floor.

typedef float f32x4 __attribute__((ext_vector_type(4)));
typedef __bf16 bf16x8 __attribute__((ext_vector_type(8)));

#define TDIM 2048L
#define UDIM 512L
#define ST32 16384L     // elems per [32,512] state
#define ST64 32768L     // elems per [64,512] tile
#define TS 262144L      // elems per frag term
#define FE 786432L      // elems per 3-term frag matrix
#define PP 520          // padded plane row stride (bf16 elems)

__device__ __forceinline__ f32x4 mfma16(bf16x8 a, bf16x8 b, f32x4 c) {
  return __builtin_amdgcn_mfma_f32_16x16x32_bf16(a, b, c, 0, 0, 0);
}

// fp32 [32][512] swizzle (staging for sq/pair/down)
__device__ __forceinline__ int hidx(int row, int col) {
  return row * 512 + (col ^ ((row & 7) << 3));
}

__device__ __forceinline__ void pack8(const f32x4& v0, const f32x4& v1,
                                      bf16x8& hv, bf16x8& lv) {
#pragma unroll
  for (int j = 0; j < 4; ++j) {
    const float a = v0[j];
    const __bf16 ha = (__bf16)a;
    hv[j] = ha; lv[j] = (__bf16)(a - (float)ha);
    const float b = v1[j];
    const __bf16 hb = (__bf16)b;
    hv[j + 4] = hb; lv[j + 4] = (__bf16)(b - (float)hb);
  }
}

// ---- M=32 pair-plane helpers (stride PP, blockDim-stride loops) -----------

__device__ __forceinline__ void stage32p(const float* __restrict__ src,
                                         long pitch, __bf16* Phi, __bf16* Plo) {
  for (int i = threadIdx.x; i < 2048; i += blockDim.x) {
    const int row = i >> 6, cb = i & 63;
    const float* p = src + (long)row * pitch + cb * 8;
    bf16x8 hv, lv;
    pack8(*(const f32x4*)p, *(const f32x4*)(p + 4), hv, lv);
    const int o = row * PP + cb * 8;
    *(bf16x8*)(Phi + o) = hv;
    *(bf16x8*)(Plo + o) = lv;
  }
}

__device__ __forceinline__ void write_bt(const __bf16* Phi, const __bf16* Plo,
                                         float* out, long t) {
  for (int i = threadIdx.x; i < 2048; i += blockDim.x) {
    const int row = i >> 6, cb = i & 63;
    const int o = row * PP + cb * 8;
    const bf16x8 hv = *(const bf16x8*)(Phi + o);
    const bf16x8 lv = *(const bf16x8*)(Plo + o);
    f32x4 o0, o1;
#pragma unroll
    for (int j = 0; j < 4; ++j) {
      o0[j] = (float)hv[j] + (float)lv[j];
      o1[j] = (float)hv[j + 4] + (float)lv[j + 4];
    }
    float* dst = out + (long)row * (TDIM * UDIM) + t * UDIM + cb * 8;
    *(f32x4*)dst = o0;
    *(f32x4*)(dst + 4) = o1;
  }
}

__device__ __forceinline__ void write_flat(const __bf16* Phi, const __bf16* Plo,
                                           float* dst) {
  for (int i = threadIdx.x; i < 2048; i += blockDim.x) {
    const int row = i >> 6, cb = i & 63;
    const int o = row * PP + cb * 8;
    const bf16x8 hv = *(const bf16x8*)(Phi + o);
    const bf16x8 lv = *(const bf16x8*)(Plo + o);
    f32x4 o0, o1;
#pragma unroll
    for (int j = 0; j < 4; ++j) {
      o0[j] = (float)hv[j] + (float)lv[j];
      o1[j] = (float)hv[j + 4] + (float)lv[j + 4];
    }
    float* d = dst + row * 512 + cb * 8;
    *(f32x4*)d = o0;
    *(f32x4*)(d + 4) = o1;
  }
}

// One step on M=32 planes (1024 thr, 16 waves, wave owns 2 nt).
// addbase/addpitch: addend element = addbase[bat*addpitch + col].
template <int NTERM, int NPROD, bool HAS_H>
__device__ __forceinline__ void pstep32(__bf16* Phi, __bf16* Plo,
                                        const __bf16* __restrict__ bfrag,
                                        const float* __restrict__ addbase,
                                        long addpitch) {
  const int tid = threadIdx.x, l = tid & 63, w = tid >> 6, g = l >> 4, li = l & 15;
  f32x4 addv[2][2];
#pragma unroll
  for (int mt = 0; mt < 2; ++mt)
#pragma unroll
    for (int q = 0; q < 2; ++q) {
      const int col = (w * 2 + q) * 16 + li;
#pragma unroll
      for (int r = 0; r < 4; ++r) {
        const int bat = mt * 16 + g * 4 + r;
        addv[mt][q][r] = addbase[(long)bat * addpitch + col];
      }
    }

  f32x4 acc[2][2] = {};
  if (HAS_H) {
#pragma unroll 4
    for (int kk = 0; kk < 16; ++kk) {
      bf16x8 b[NTERM][2];
#pragma unroll
      for (int q = 0; q < 2; ++q) {
        const long fo = (((long)(w * 2 + q) * 16 + kk) * 64 + l) * 8;
#pragma unroll
        for (int tt = 0; tt < NTERM; ++tt)
          b[tt][q] = *(const bf16x8*)(bfrag + (long)tt * TS + fo);
      }
#pragma unroll
      for (int mt = 0; mt < 2; ++mt) {
        const int o = (mt * 16 + li) * PP + kk * 32 + g * 8;
        const bf16x8 a1 = *(const bf16x8*)(Phi + o);
        const bf16x8 a2 = *(const bf16x8*)(Plo + o);
#pragma unroll
        for (int q = 0; q < 2; ++q) {
          acc[mt][q] = mfma16(a1, b[0][q], acc[mt][q]);
          acc[mt][q] = mfma16(a1, b[1][q], acc[mt][q]);
          if (NPROD >= 3) acc[mt][q] = mfma16(a2, b[0][q], acc[mt][q]);
          if (NPROD >= 4) acc[mt][q] = mfma16(a1, b[NTERM - 1][q], acc[mt][q]);
        }
      }
    }
    __syncthreads();  // plane reads done before overwrite
  }

#pragma unroll
  for (int mt = 0; mt < 2; ++mt)
#pragma unroll
    for (int q = 0; q < 2; ++q) {
      const int col = (w * 2 + q) * 16 + li;
#pragma unroll
      for (int r = 0; r < 4; ++r) {
        const float v = (HAS_H ? acc[mt][q][r] : 0.0f) + addv[mt][q][r];
        const int row = mt * 16 + g * 4 + r;
        const __bf16 hi = (__bf16)v;
        const int o = row * PP + col;
        Phi[o] = hi;
        Plo[o] = (__bf16)(v - (float)hi);
      }
    }
  __syncthreads();
}

// Double step: h <- h@R^2 + xw[t1]@R + xw[t2]  (k_local, 1024 thr)
__device__ __forceinline__ void dstep(__bf16* Phi, __bf16* Plo,
                                      __bf16* Qhi, __bf16* Qlo,
                                      const __bf16* __restrict__ r2f,
                                      const __bf16* __restrict__ rf,
                                      const float* __restrict__ xw,
                                      long t1, long t2) {
  stage32p(xw + t1 * UDIM, TDIM * UDIM, Qhi, Qlo);
  __syncthreads();
  const int tid = threadIdx.x, l = tid & 63, w = tid >> 6, g = l >> 4, li = l & 15;
  f32x4 addv[2][2];
#pragma unroll
  for (int mt = 0; mt < 2; ++mt)
#pragma unroll
    for (int q = 0; q < 2; ++q) {
      const int col = (w * 2 + q) * 16 + li;
#pragma unroll
      for (int r = 0; r < 4; ++r) {
        const int bat = mt * 16 + g * 4 + r;
        addv[mt][q][r] = xw[(long)bat * (TDIM * UDIM) + t2 * UDIM + col];
      }
    }
  f32x4 acc[2][2] = {};
#pragma unroll 2
  for (int kk = 0; kk < 16; ++kk) {
    bf16x8 c0[2], c1[2], d0[2], d1[2];
#pragma unroll
    for (int q = 0; q < 2; ++q) {
      const long fo = (((long)(w * 2 + q) * 16 + kk) * 64 + l) * 8;
      c0[q] = *(const bf16x8*)(r2f + fo);
      c1[q] = *(const bf16x8*)(r2f + TS + fo);
      d0[q] = *(const bf16x8*)(rf + fo);
      d1[q] = *(const bf16x8*)(rf + TS + fo);
    }
#pragma unroll
    for (int mt = 0; mt < 2; ++mt) {
      const int o = (mt * 16 + li) * PP + kk * 32 + g * 8;
      const bf16x8 h1 = *(const bf16x8*)(Phi + o);
      const bf16x8 h2 = *(const bf16x8*)(Plo + o);
      const bf16x8 q1 = *(const bf16x8*)(Qhi + o);
      const bf16x8 q2 = *(const bf16x8*)(Qlo + o);
#pragma unroll
      for (int q = 0; q < 2; ++q) {
        acc[mt][q] = mfma16(h1, c0[q], acc[mt][q]);
        acc[mt][q] = mfma16(q1, d0[q], acc[mt][q]);
        acc[mt][q] = mfma16(h1, c1[q], acc[mt][q]);
        acc[mt][q] = mfma16(q1, d1[q], acc[mt][q]);
        acc[mt][q] = mfma16(h2, c0[q], acc[mt][q]);
        acc[mt][q] = mfma16(q2, d0[q], acc[mt][q]);
      }
    }
  }
  __syncthreads();
#pragma unroll
  for (int mt = 0; mt < 2; ++mt)
#pragma unroll
    for (int q = 0; q < 2; ++q) {
      const int col = (w * 2 + q) * 16 + li;
#pragma unroll
      for (int r = 0; r < 4; ++r) {
        const float v = acc[mt][q][r] + addv[mt][q][r];
        const int row = mt * 16 + g * 4 + r;
        const __bf16 hi = (__bf16)v;
        const int o = row * PP + col;
        Phi[o] = hi;
        Plo[o] = (__bf16)(v - (float)hi);
      }
    }
  __syncthreads();
}

// ---- device tasks ----------------------------------------------------------

// xW task, M=64: 512 thr = 8 waves; wave owns 4 nt; mt=0..3. W 1-term.
__device__ __forceinline__ void xw_dev(long blk, const float* __restrict__ x,
                                       const __bf16* __restrict__ wf,
                                       float* __restrict__ out, char* smem) {
  __bf16* Phi = (__bf16*)smem;  // [64][PP] hi-only = 66560 B
  const float* src = x + blk * ST64;
  for (int i = threadIdx.x; i < 4096; i += 512) {
    const int row = i >> 6, cb = i & 63;
    const f32x4 v0 = *(const f32x4*)(src + (long)row * 512 + cb * 8);
    const f32x4 v1 = *(const f32x4*)(src + (long)row * 512 + cb * 8 + 4);
    bf16x8 hv;
#pragma unroll
    for (int j = 0; j < 4; ++j) {
      hv[j] = (__bf16)v0[j];
      hv[j + 4] = (__bf16)v1[j];
    }
    *(bf16x8*)(Phi + row * PP + cb * 8) = hv;
  }
  __syncthreads();
  const int tid = threadIdx.x, l = tid & 63, w = tid >> 6, g = l >> 4, li = l & 15;
  f32x4 acc[4][4] = {};
#pragma unroll 4
  for (int kk = 0; kk < 16; ++kk) {
    bf16x8 b0[4];
#pragma unroll
    for (int q = 0; q < 4; ++q) {
      const long fo = (((long)(w * 4 + q) * 16 + kk) * 64 + l) * 8;
      b0[q] = *(const bf16x8*)(wf + fo);
    }
#pragma unroll
    for (int mt = 0; mt < 4; ++mt) {
      const bf16x8 a1 = *(const bf16x8*)(Phi + (mt * 16 + li) * PP + kk * 32 + g * 8);
#pragma unroll
      for (int q = 0; q < 4; ++q)
        acc[mt][q] = mfma16(a1, b0[q], acc[mt][q]);
    }
  }
  float* gdst = out + blk * ST64;
#pragma unroll
  for (int mt = 0; mt < 4; ++mt)
#pragma unroll
    for (int q = 0; q < 4; ++q) {
      const int col = (w * 4 + q) * 16 + li;
#pragma unroll
      for (int r = 0; r < 4; ++r)
        gdst[(long)(mt * 16 + g * 4 + r) * 512 + col] = acc[mt][q][r];
    }
}

// Stage a [32,512] fp32 state into swizzled LDS (512 thr).
__device__ __forceinline__ void stage_sw(const float* __restrict__ src,
                                         float* hbuf) {
  for (int i = threadIdx.x; i < 4096; i += 512) {
    const int flat = i * 4, row = flat >> 9, col = flat & 511;
    *(f32x4*)&hbuf[hidx(row, col)] = *(const f32x4*)&src[flat];
  }
}

// A @ Bfrag with A in swizzled LDS (2-term, 3 products).
__device__ __forceinline__ f32x4 lds_mm(const float* hbuf,
                                        const __bf16* __restrict__ bf,
                                        int mt, int ntg) {
  const int tid = threadIdx.x, l = tid & 63, g = (l >> 4) & 3, li = l & 15;
  f32x4 acc = {};
#pragma unroll 2
  for (int kk = 0; kk < 16; ++kk) {
    const long fo = (((long)ntg * 16 + kk) * 64 + l) * 8;
    const bf16x8 b0 = *(const bf16x8*)(bf + fo);
    const bf16x8 b1 = *(const bf16x8*)(bf + TS + fo);
    bf16x8 a1, a2;
    const float* pp = &hbuf[hidx(mt * 16 + li, kk * 32 + g * 8)];
#pragma unroll
    for (int j = 0; j < 8; ++j) {
      const float v = pp[j];
      const __bf16 hi = (__bf16)v;
      a1[j] = hi;
      a2[j] = (__bf16)(v - (float)hi);
    }
    acc = mfma16(a1, b0, acc);
    acc = mfma16(a1, b1, acc);
    acc = mfma16(a2, b0, acc);
  }
  return acc;
}

// Multiply task (128 blocks x 512 thr): out = A @ Bfrag, fp32 + frag split.
__device__ __forceinline__ void sq_dev(int b, const float* __restrict__ a,
                                       const __bf16* __restrict__ bf,
                                       float* __restrict__ of32,
                                       __bf16* __restrict__ ofr, float* hbuf) {
  const int rg = b >> 3, cg = b & 7;
  const int tid = threadIdx.x, l = tid & 63, w = tid >> 6, g = l >> 4, li = l & 15;
  stage_sw(a + (long)rg * ST32, hbuf);
  __syncthreads();
  const int mt = w >> 2, q = w & 3, ntg = cg * 4 + q;
  f32x4 acc = {};
#pragma unroll 2
  for (int kk = 0; kk < 16; ++kk) {
    const long fo = (((long)ntg * 16 + kk) * 64 + l) * 8;
    const bf16x8 b0 = *(const bf16x8*)(bf + fo);
    const bf16x8 b1 = *(const bf16x8*)(bf + TS + fo);
    const bf16x8 b2 = *(const bf16x8*)(bf + 2 * TS + fo);
    bf16x8 a1, a2;
    const float* pp = &hbuf[hidx(mt * 16 + li, kk * 32 + g * 8)];
#pragma unroll
    for (int j = 0; j < 8; ++j) {
      const float v = pp[j];
      const __bf16 hi = (__bf16)v;
      a1[j] = hi;
      a2[j] = (__bf16)(v - (float)hi);
    }
    acc = mfma16(a1, b0, acc);
    acc = mfma16(a1, b1, acc);
    acc = mfma16(a2, b0, acc);
    acc = mfma16(a1, b2, acc);
  }
  const int n = ntg * 16 + li;
#pragma unroll
  for (int r = 0; r < 4; ++r) {
    const int k = rg * 32 + mt * 16 + g * 4 + r;
    const float v = acc[r];
    of32[(long)k * 512 + n] = v;
    const __bf16 t1 = (__bf16)v;
    const float r1 = v - (float)t1;
    const __bf16 t2 = (__bf16)r1;
    const long fi = (((long)(n >> 4) * 16 + (k >> 5)) * 64 + ((k >> 3) & 3) * 16 + (n & 15)) * 8 + (k & 7);
    ofr[fi] = t1;
    ofr[TS + fi] = t2;
    ofr[2 * TS + fi] = (__bf16)(r1 - (float)t2);
  }
}

// Tree up-stage task (LDS-staged A): out[p] = in[2p] @ M + in[2p+1].
__device__ __forceinline__ void pair_dev(int b, const float* __restrict__ in,
                                         const __bf16* __restrict__ bf,
                                         float* __restrict__ outb, float* hbuf) {
  const int p = b >> 3, cs = b & 7;
  const int tid = threadIdx.x, l = tid & 63, w = tid >> 6, g = l >> 4, li = l & 15;
  stage_sw(in + (long)(2 * p) * ST32, hbuf);
  __syncthreads();
  const int mt = w >> 2, ntg = cs * 4 + (w & 3);
  const f32x4 acc = lds_mm(hbuf, bf, mt, ntg);
  const float* addp = in + (long)(2 * p + 1) * ST32;
  float* outp = outb + (long)p * ST32;
  const int col = ntg * 16 + li;
#pragma unroll
  for (int r = 0; r < 4; ++r) {
    const int row = mt * 16 + g * 4 + r;
    outp[(long)row * 512 + col] = acc[r] + addp[(long)row * 512 + col];
  }
}

// ---- kernels --------------------------------------------------------------

// Split two fp32 512x512 matrices into 3 bf16 terms (MFMA B-fragment order).
__global__ __launch_bounds__(512) void k_split2(const float* __restrict__ m0,
                                                const float* __restrict__ m1,
                                                __bf16* __restrict__ f0,
                                                __bf16* __restrict__ f1) {
  const int bb = blockIdx.x;
  const float* m = (bb < 512) ? m0 : m1;
  __bf16* f = (bb < 512) ? f0 : f1;
  const int idx = (bb & 511) * 512 + threadIdx.x;
  const int j = idx & 7, l = (idx >> 3) & 63, kk = (idx >> 9) & 15, nt = idx >> 13;
  const int k = kk * 32 + (l >> 4) * 8 + j;
  const int n = nt * 16 + (l & 15);
  const float v = m[k * 512 + n];
  const __bf16 t1 = (__bf16)v;
  const float r1 = v - (float)t1;
  const __bf16 t2 = (__bf16)r1;
  f[idx] = t1;
  f[TS + idx] = t2;
  f[2 * TS + idx] = (__bf16)(r1 - (float)t2);
}

// xW remainder kernel (base = first M=64 tile index).
__global__ __launch_bounds__(512) void k_xw(const float* __restrict__ x,
                                            const __bf16* __restrict__ wf,
                                            float* __restrict__ out, int base) {
  __shared__ __align__(16) char smem[64 * PP * 2];
  xw_dev(base + blockIdx.x, x, wf, out, smem);
}

// Co-dispatch: blocks 0-127 advance squaring chain; blocks 128+ do xw tiles.
__global__ __launch_bounds__(512) void k_xwsq(const float* __restrict__ sqa,
                                              const __bf16* __restrict__ sqbf,
                                              float* __restrict__ sqo32,
                                              __bf16* __restrict__ sqofr,
                                              const float* __restrict__ x,
                                              const __bf16* __restrict__ wf,
                                              float* __restrict__ out, int base) {
  __shared__ __align__(16) char smem[64 * PP * 2];
  const int b = blockIdx.x;
  if (b < 128)
    sq_dev(b, sqa, sqbf, sqo32, sqofr, (float*)smem);
  else
    xw_dev(base + (b - 128), x, wf, out, smem);
}

// Co-dispatch: blocks 0-127 squaring; blocks 128+ tree up-stage.
__global__ __launch_bounds__(512) void k_combo(const float* __restrict__ sqa,
                                               const __bf16* __restrict__ sqbf,
                                               float* __restrict__ sqo32,
                                               __bf16* __restrict__ sqofr,
                                               const float* __restrict__ prin,
                                               const __bf16* __restrict__ prbf,
                                               float* __restrict__ prout) {
  __shared__ float hbuf[ST32];
  const int b = blockIdx.x;
  if (b < 128)
    sq_dev(b, sqa, sqbf, sqo32, sqofr, hbuf);
  else
    pair_dev(b - 128, prin, prbf, prout, hbuf);
}

// Level-0 up-sweep: h = xw[t0]; 1 single step; 3 double steps. 2-term R.
__global__ __launch_bounds__(1024) void k_local(const float* __restrict__ xw,
                                                const __bf16* __restrict__ rf,
                                                const __bf16* __restrict__ r2f,
                                                float* __restrict__ sout) {
  __shared__ __bf16 Phi[32 * PP], Plo[32 * PP], Qhi[32 * PP], Qlo[32 * PP];
  const long c = blockIdx.x;
  stage32p(xw + c * 8 * UDIM, TDIM * UDIM, Phi, Plo);  // h = xw[t0]
  __syncthreads();
  pstep32<2, 3, true>(Phi, Plo, rf, xw + (c * 8 + 1) * UDIM, TDIM * UDIM);
  dstep(Phi, Plo, Qhi, Qlo, r2f, rf, xw, c * 8 + 2, c * 8 + 3);
  dstep(Phi, Plo, Qhi, Qlo, r2f, rf, xw, c * 8 + 4, c * 8 + 5);
  dstep(Phi, Plo, Qhi, Qlo, r2f, rf, xw, c * 8 + 6, c * 8 + 7);
  write_flat(Phi, Plo, sout + c * ST32);
}

// Final pass, with fused down-k=1:
//   even chunk c=2p:  entry = E1[p]
//   odd  chunk c=2p+1: entry = E1[p]@R^8 + S[2p]
// then 8 serial steps writing h into out.
__global__ __launch_bounds__(1024) void k_fix0(const float* __restrict__ e1,
                                               const float* __restrict__ sbuf,
                                               float* out,
                                               const __bf16* __restrict__ rf,
                                               const __bf16* __restrict__ r8f) {
  __shared__ __bf16 Phi[32 * PP], Plo[32 * PP];
  const long c = blockIdx.x;
  stage32p(e1 + (c >> 1) * ST32, 512, Phi, Plo);
  __syncthreads();
  if (c & 1)
    pstep32<2, 3, true>(Phi, Plo, r8f, sbuf + (c - 1) * ST32, 512);
  for (int j = 0; j < 8; ++j) {
    pstep32<2, 3, true>(Phi, Plo, rf, out + (c * 8 + j) * UDIM, TDIM * UDIM);
    write_bt(Phi, Plo, out, c * 8 + j);
  }
}

// Tree down-stage (LDS-staged parent), in place into child-level buffer:
//   ulev[2p+1] = epar[p] @ M + ulev[2p];  ulev[2p] = epar[p]
__global__ __launch_bounds__(512) void k_down(const float* __restrict__ epar,
                                              float* __restrict__ ulev,
                                              const __bf16* __restrict__ bf) {
  __shared__ float hbuf[ST32];
  const int p = blockIdx.x >> 3, cs = blockIdx.x & 7;
  const int tid = threadIdx.x, l = tid & 63, w = tid >> 6, g = l >> 4, li = l & 15;
  stage_sw(epar + (long)p * ST32, hbuf);
  __syncthreads();
  const int mt = w >> 2, ntg = cs * 4 + (w & 3);
  const f32x4 acc = lds_mm(hbuf, bf, mt, ntg);
  float* evp = ulev + (long)(2 * p) * ST32;
  float* outp = ulev + (long)(2 * p + 1) * ST32;
  const int col = ntg * 16 + li;
  float cp[4];
#pragma unroll
  for (int r = 0; r < 4; ++r) {
    const int row = mt * 16 + g * 4 + r;
    const long off = (long)row * 512 + col;
    cp[r] = hbuf[hidx(row, col)];     // = epar[p][row][col], exact
    outp[off] = acc[r] + evp[off];
  }
  __syncthreads();
#pragma unroll
  for (int r = 0; r < 4; ++r) {
    const int row = mt * 16 + g * 4 + r;
    evp[(long)row * 512 + col] = cp[r];
  }
}

extern "C" void kernel_launch(void* const* d_in, const int* in_sizes, int n_in,
                              void* d_out, int out_size, void* d_ws, size_t ws_size,
                              hipStream_t stream) {
  (void)in_sizes; (void)n_in; (void)out_size; (void)ws_size;
  const float* x  = (const float*)d_in[0];
  const float* W  = (const float*)d_in[1];
  const float* R  = (const float*)d_in[2];
  const float* h0 = (const float*)d_in[3];
  float* out = (float*)d_out;

  __bf16* F  = (__bf16*)d_ws;          // F[i] = frags of R^(2^i), i=0..10
  __bf16* Fw = F + 11 * FE;            // frags of W
  float* P1 = (float*)(Fw + FE);
  float* P2 = P1 + TS;
  float* Sbuf = P2 + TS;               // 256 chunk sums (S) -- preserved
  float* Ub[8];
  {
    float* up = Sbuf + 256 * ST32;
    for (int k = 1; k <= 7; ++k) { Ub[k] = up; up += (1L << (8 - k)) * ST32; }
  }

  k_split2<<<1024, 512, 0, stream>>>(W, R, Fw, F);

  // Head squarings co-dispatched with xw slices (256 M=64 tiles each):
  //   F[1]=R^2 ; F[2]=R^4 ; F[3]=R^8  (fp32 ping-pong, frag split fused)
  k_xwsq<<<384, 512, 0, stream>>>(R, F, P1, F + FE, x, Fw, out, 0);
  k_xwsq<<<384, 512, 0, stream>>>(P1, F + FE, P2, F + 2L * FE, x, Fw, out, 256);
  k_xwsq<<<384, 512, 0, stream>>>(P2, F + 2L * FE, P1, F + 3L * FE, x, Fw, out, 512);
  k_xw<<<256, 512, 0, stream>>>(x, Fw, out, 768);

  k_local<<<256, 1024, 0, stream>>>(out, F, F + FE, Sbuf);

  // phases k=1..7: sq (F[k+3] <- F[k+2], fp32 ping-pong) || tree-up stage k
  for (int k = 1; k <= 7; ++k) {
    const int i = k + 3;  // chain index being produced
    const float* sqa = (i & 1) ? P2 : P1;   // fp32 of R^(2^(i-1))
    float* sqo = (i & 1) ? P1 : P2;
    const float* prin = (k == 1) ? Sbuf : Ub[k - 1];
    const int npr = (1 << (8 - k)) * 8;
    k_combo<<<128 + npr, 512, 0, stream>>>(sqa, F + (long)(i - 1) * FE, sqo,
                                           F + (long)i * FE, prin,
                                           F + (long)(k + 2) * FE, Ub[k]);
  }

  // down-sweep k=7..2 (k=1 fused into fix0); E1 lands in Ub[1], S stays in Sbuf
  k_down<<<8, 512, 0, stream>>>(h0, Ub[7], F + 10L * FE);
  for (int k = 7; k >= 2; --k)
    k_down<<<(1 << (8 - k)) * 8, 512, 0, stream>>>(Ub[k], Ub[k - 1], F + (long)(k + 2) * FE);

  k_fix0<<<256, 1024, 0, stream>>>(Ub[1], Sbuf, out, F, F + 3L * FE);
}

// Round 15
// 461.480 us; speedup vs baseline: 1.4777x; 1.0589x over previous
//
#include <hip/hip_runtime.h>
#include <hip/hip_bf16.h>

// Linear recurrence h_t = x_t@W + h_{t-1}@R, parallel scan, chunk C=8.
// R15 = R14 (488us) + fix0 uses 1-term R (2 products: h_hi*R_hi + h_lo*R_hi).
// Safe because fix0 errors are CHUNK-LOCAL (outputs final, no propagation
// through the tree); k_local must stay 2-term (its errors random-walk over
// all 2048 steps). Frag ingest/step in fix0: 1 MB -> 0.5 MB.

typedef float f32x4 __attribute__((ext_vector_type(4)));
typedef __bf16 bf16x8 __attribute__((ext_vector_type(8)));

#define TDIM 2048L
#define UDIM 512L
#define ST32 16384L     // elems per [32,512] state
#define ST64 32768L     // elems per [64,512] tile
#define TS 262144L      // elems per frag term
#define FE 786432L      // elems per 3-term frag matrix
#define PP 520          // padded plane row stride (bf16 elems)

__device__ __forceinline__ f32x4 mfma16(bf16x8 a, bf16x8 b, f32x4 c) {
  return __builtin_amdgcn_mfma_f32_16x16x32_bf16(a, b, c, 0, 0, 0);
}

// fp32 [32][512] swizzle (staging for sq/pair/down)
__device__ __forceinline__ int hidx(int row, int col) {
  return row * 512 + (col ^ ((row & 7) << 3));
}

__device__ __forceinline__ void pack8(const f32x4& v0, const f32x4& v1,
                                      bf16x8& hv, bf16x8& lv) {
#pragma unroll
  for (int j = 0; j < 4; ++j) {
    const float a = v0[j];
    const __bf16 ha = (__bf16)a;
    hv[j] = ha; lv[j] = (__bf16)(a - (float)ha);
    const float b = v1[j];
    const __bf16 hb = (__bf16)b;
    hv[j + 4] = hb; lv[j + 4] = (__bf16)(b - (float)hb);
  }
}

// ---- M=32 pair-plane helpers (stride PP, blockDim-stride loops) -----------

__device__ __forceinline__ void stage32p(const float* __restrict__ src,
                                         long pitch, __bf16* Phi, __bf16* Plo) {
  for (int i = threadIdx.x; i < 2048; i += blockDim.x) {
    const int row = i >> 6, cb = i & 63;
    const float* p = src + (long)row * pitch + cb * 8;
    bf16x8 hv, lv;
    pack8(*(const f32x4*)p, *(const f32x4*)(p + 4), hv, lv);
    const int o = row * PP + cb * 8;
    *(bf16x8*)(Phi + o) = hv;
    *(bf16x8*)(Plo + o) = lv;
  }
}

__device__ __forceinline__ void write_bt(const __bf16* Phi, const __bf16* Plo,
                                         float* out, long t) {
  for (int i = threadIdx.x; i < 2048; i += blockDim.x) {
    const int row = i >> 6, cb = i & 63;
    const int o = row * PP + cb * 8;
    const bf16x8 hv = *(const bf16x8*)(Phi + o);
    const bf16x8 lv = *(const bf16x8*)(Plo + o);
    f32x4 o0, o1;
#pragma unroll
    for (int j = 0; j < 4; ++j) {
      o0[j] = (float)hv[j] + (float)lv[j];
      o1[j] = (float)hv[j + 4] + (float)lv[j + 4];
    }
    float* dst = out + (long)row * (TDIM * UDIM) + t * UDIM + cb * 8;
    *(f32x4*)dst = o0;
    *(f32x4*)(dst + 4) = o1;
  }
}

__device__ __forceinline__ void write_flat(const __bf16* Phi, const __bf16* Plo,
                                           float* dst) {
  for (int i = threadIdx.x; i < 2048; i += blockDim.x) {
    const int row = i >> 6, cb = i & 63;
    const int o = row * PP + cb * 8;
    const bf16x8 hv = *(const bf16x8*)(Phi + o);
    const bf16x8 lv = *(const bf16x8*)(Plo + o);
    f32x4 o0, o1;
#pragma unroll
    for (int j = 0; j < 4; ++j) {
      o0[j] = (float)hv[j] + (float)lv[j];
      o1[j] = (float)hv[j + 4] + (float)lv[j + 4];
    }
    float* d = dst + row * 512 + cb * 8;
    *(f32x4*)d = o0;
    *(f32x4*)(d + 4) = o1;
  }
}

// One step on M=32 planes (1024 thr, 16 waves, wave owns 2 nt).
// Product emission: a1*b0 always; a1*b1 if NTERM>=2; a2*b0 if NPROD>NTERM;
// a1*b[NTERM-1] again if NPROD>=4. <2,3>: a1b0,a1b1,a2b0. <1,2>: a1b0,a2b0.
template <int NTERM, int NPROD, bool HAS_H>
__device__ __forceinline__ void pstep32(__bf16* Phi, __bf16* Plo,
                                        const __bf16* __restrict__ bfrag,
                                        const float* __restrict__ addbase,
                                        long addpitch) {
  const int tid = threadIdx.x, l = tid & 63, w = tid >> 6, g = l >> 4, li = l & 15;
  f32x4 addv[2][2];
#pragma unroll
  for (int mt = 0; mt < 2; ++mt)
#pragma unroll
    for (int q = 0; q < 2; ++q) {
      const int col = (w * 2 + q) * 16 + li;
#pragma unroll
      for (int r = 0; r < 4; ++r) {
        const int bat = mt * 16 + g * 4 + r;
        addv[mt][q][r] = addbase[(long)bat * addpitch + col];
      }
    }

  f32x4 acc[2][2] = {};
  if (HAS_H) {
#pragma unroll 4
    for (int kk = 0; kk < 16; ++kk) {
      bf16x8 b[NTERM][2];
#pragma unroll
      for (int q = 0; q < 2; ++q) {
        const long fo = (((long)(w * 2 + q) * 16 + kk) * 64 + l) * 8;
#pragma unroll
        for (int tt = 0; tt < NTERM; ++tt)
          b[tt][q] = *(const bf16x8*)(bfrag + (long)tt * TS + fo);
      }
#pragma unroll
      for (int mt = 0; mt < 2; ++mt) {
        const int o = (mt * 16 + li) * PP + kk * 32 + g * 8;
        const bf16x8 a1 = *(const bf16x8*)(Phi + o);
        const bf16x8 a2 = *(const bf16x8*)(Plo + o);
#pragma unroll
        for (int q = 0; q < 2; ++q) {
          acc[mt][q] = mfma16(a1, b[0][q], acc[mt][q]);
          if (NTERM >= 2) acc[mt][q] = mfma16(a1, b[1][q], acc[mt][q]);
          if (NPROD > NTERM) acc[mt][q] = mfma16(a2, b[0][q], acc[mt][q]);
          if (NPROD >= 4) acc[mt][q] = mfma16(a1, b[NTERM - 1][q], acc[mt][q]);
        }
      }
    }
    __syncthreads();  // plane reads done before overwrite
  }

#pragma unroll
  for (int mt = 0; mt < 2; ++mt)
#pragma unroll
    for (int q = 0; q < 2; ++q) {
      const int col = (w * 2 + q) * 16 + li;
#pragma unroll
      for (int r = 0; r < 4; ++r) {
        const float v = (HAS_H ? acc[mt][q][r] : 0.0f) + addv[mt][q][r];
        const int row = mt * 16 + g * 4 + r;
        const __bf16 hi = (__bf16)v;
        const int o = row * PP + col;
        Phi[o] = hi;
        Plo[o] = (__bf16)(v - (float)hi);
      }
    }
  __syncthreads();
}

// Double step: h <- h@R^2 + xw[t1]@R + xw[t2]  (k_local, 1024 thr)
__device__ __forceinline__ void dstep(__bf16* Phi, __bf16* Plo,
                                      __bf16* Qhi, __bf16* Qlo,
                                      const __bf16* __restrict__ r2f,
                                      const __bf16* __restrict__ rf,
                                      const float* __restrict__ xw,
                                      long t1, long t2) {
  stage32p(xw + t1 * UDIM, TDIM * UDIM, Qhi, Qlo);
  __syncthreads();
  const int tid = threadIdx.x, l = tid & 63, w = tid >> 6, g = l >> 4, li = l & 15;
  f32x4 addv[2][2];
#pragma unroll
  for (int mt = 0; mt < 2; ++mt)
#pragma unroll
    for (int q = 0; q < 2; ++q) {
      const int col = (w * 2 + q) * 16 + li;
#pragma unroll
      for (int r = 0; r < 4; ++r) {
        const int bat = mt * 16 + g * 4 + r;
        addv[mt][q][r] = xw[(long)bat * (TDIM * UDIM) + t2 * UDIM + col];
      }
    }
  f32x4 acc[2][2] = {};
#pragma unroll 2
  for (int kk = 0; kk < 16; ++kk) {
    bf16x8 c0[2], c1[2], d0[2], d1[2];
#pragma unroll
    for (int q = 0; q < 2; ++q) {
      const long fo = (((long)(w * 2 + q) * 16 + kk) * 64 + l) * 8;
      c0[q] = *(const bf16x8*)(r2f + fo);
      c1[q] = *(const bf16x8*)(r2f + TS + fo);
      d0[q] = *(const bf16x8*)(rf + fo);
      d1[q] = *(const bf16x8*)(rf + TS + fo);
    }
#pragma unroll
    for (int mt = 0; mt < 2; ++mt) {
      const int o = (mt * 16 + li) * PP + kk * 32 + g * 8;
      const bf16x8 h1 = *(const bf16x8*)(Phi + o);
      const bf16x8 h2 = *(const bf16x8*)(Plo + o);
      const bf16x8 q1 = *(const bf16x8*)(Qhi + o);
      const bf16x8 q2 = *(const bf16x8*)(Qlo + o);
#pragma unroll
      for (int q = 0; q < 2; ++q) {
        acc[mt][q] = mfma16(h1, c0[q], acc[mt][q]);
        acc[mt][q] = mfma16(q1, d0[q], acc[mt][q]);
        acc[mt][q] = mfma16(h1, c1[q], acc[mt][q]);
        acc[mt][q] = mfma16(q1, d1[q], acc[mt][q]);
        acc[mt][q] = mfma16(h2, c0[q], acc[mt][q]);
        acc[mt][q] = mfma16(q2, d0[q], acc[mt][q]);
      }
    }
  }
  __syncthreads();
#pragma unroll
  for (int mt = 0; mt < 2; ++mt)
#pragma unroll
    for (int q = 0; q < 2; ++q) {
      const int col = (w * 2 + q) * 16 + li;
#pragma unroll
      for (int r = 0; r < 4; ++r) {
        const float v = acc[mt][q][r] + addv[mt][q][r];
        const int row = mt * 16 + g * 4 + r;
        const __bf16 hi = (__bf16)v;
        const int o = row * PP + col;
        Phi[o] = hi;
        Plo[o] = (__bf16)(v - (float)hi);
      }
    }
  __syncthreads();
}

// ---- device tasks ----------------------------------------------------------

// xW task, M=64: 512 thr = 8 waves; wave owns 4 nt; mt=0..3. W 1-term.
__device__ __forceinline__ void xw_dev(long blk, const float* __restrict__ x,
                                       const __bf16* __restrict__ wf,
                                       float* __restrict__ out, char* smem) {
  __bf16* Phi = (__bf16*)smem;  // [64][PP] hi-only = 66560 B
  const float* src = x + blk * ST64;
  for (int i = threadIdx.x; i < 4096; i += 512) {
    const int row = i >> 6, cb = i & 63;
    const f32x4 v0 = *(const f32x4*)(src + (long)row * 512 + cb * 8);
    const f32x4 v1 = *(const f32x4*)(src + (long)row * 512 + cb * 8 + 4);
    bf16x8 hv;
#pragma unroll
    for (int j = 0; j < 4; ++j) {
      hv[j] = (__bf16)v0[j];
      hv[j + 4] = (__bf16)v1[j];
    }
    *(bf16x8*)(Phi + row * PP + cb * 8) = hv;
  }
  __syncthreads();
  const int tid = threadIdx.x, l = tid & 63, w = tid >> 6, g = l >> 4, li = l & 15;
  f32x4 acc[4][4] = {};
#pragma unroll 4
  for (int kk = 0; kk < 16; ++kk) {
    bf16x8 b0[4];
#pragma unroll
    for (int q = 0; q < 4; ++q) {
      const long fo = (((long)(w * 4 + q) * 16 + kk) * 64 + l) * 8;
      b0[q] = *(const bf16x8*)(wf + fo);
    }
#pragma unroll
    for (int mt = 0; mt < 4; ++mt) {
      const bf16x8 a1 = *(const bf16x8*)(Phi + (mt * 16 + li) * PP + kk * 32 + g * 8);
#pragma unroll
      for (int q = 0; q < 4; ++q)
        acc[mt][q] = mfma16(a1, b0[q], acc[mt][q]);
    }
  }
  float* gdst = out + blk * ST64;
#pragma unroll
  for (int mt = 0; mt < 4; ++mt)
#pragma unroll
    for (int q = 0; q < 4; ++q) {
      const int col = (w * 4 + q) * 16 + li;
#pragma unroll
      for (int r = 0; r < 4; ++r)
        gdst[(long)(mt * 16 + g * 4 + r) * 512 + col] = acc[mt][q][r];
    }
}

// Stage a [32,512] fp32 state into swizzled LDS (512 thr).
__device__ __forceinline__ void stage_sw(const float* __restrict__ src,
                                         float* hbuf) {
  for (int i = threadIdx.x; i < 4096; i += 512) {
    const int flat = i * 4, row = flat >> 9, col = flat & 511;
    *(f32x4*)&hbuf[hidx(row, col)] = *(const f32x4*)&src[flat];
  }
}

// A @ Bfrag with A in swizzled LDS (2-term, 3 products).
__device__ __forceinline__ f32x4 lds_mm(const float* hbuf,
                                        const __bf16* __restrict__ bf,
                                        int mt, int ntg) {
  const int tid = threadIdx.x, l = tid & 63, g = (l >> 4) & 3, li = l & 15;
  f32x4 acc = {};
#pragma unroll 2
  for (int kk = 0; kk < 16; ++kk) {
    const long fo = (((long)ntg * 16 + kk) * 64 + l) * 8;
    const bf16x8 b0 = *(const bf16x8*)(bf + fo);
    const bf16x8 b1 = *(const bf16x8*)(bf + TS + fo);
    bf16x8 a1, a2;
    const float* pp = &hbuf[hidx(mt * 16 + li, kk * 32 + g * 8)];
#pragma unroll
    for (int j = 0; j < 8; ++j) {
      const float v = pp[j];
      const __bf16 hi = (__bf16)v;
      a1[j] = hi;
      a2[j] = (__bf16)(v - (float)hi);
    }
    acc = mfma16(a1, b0, acc);
    acc = mfma16(a1, b1, acc);
    acc = mfma16(a2, b0, acc);
  }
  return acc;
}

// Multiply task (128 blocks x 512 thr): out = A @ Bfrag, fp32 + frag split.
__device__ __forceinline__ void sq_dev(int b, const float* __restrict__ a,
                                       const __bf16* __restrict__ bf,
                                       float* __restrict__ of32,
                                       __bf16* __restrict__ ofr, float* hbuf) {
  const int rg = b >> 3, cg = b & 7;
  const int tid = threadIdx.x, l = tid & 63, w = tid >> 6, g = l >> 4, li = l & 15;
  stage_sw(a + (long)rg * ST32, hbuf);
  __syncthreads();
  const int mt = w >> 2, q = w & 3, ntg = cg * 4 + q;
  f32x4 acc = {};
#pragma unroll 2
  for (int kk = 0; kk < 16; ++kk) {
    const long fo = (((long)ntg * 16 + kk) * 64 + l) * 8;
    const bf16x8 b0 = *(const bf16x8*)(bf + fo);
    const bf16x8 b1 = *(const bf16x8*)(bf + TS + fo);
    const bf16x8 b2 = *(const bf16x8*)(bf + 2 * TS + fo);
    bf16x8 a1, a2;
    const float* pp = &hbuf[hidx(mt * 16 + li, kk * 32 + g * 8)];
#pragma unroll
    for (int j = 0; j < 8; ++j) {
      const float v = pp[j];
      const __bf16 hi = (__bf16)v;
      a1[j] = hi;
      a2[j] = (__bf16)(v - (float)hi);
    }
    acc = mfma16(a1, b0, acc);
    acc = mfma16(a1, b1, acc);
    acc = mfma16(a2, b0, acc);
    acc = mfma16(a1, b2, acc);
  }
  const int n = ntg * 16 + li;
#pragma unroll
  for (int r = 0; r < 4; ++r) {
    const int k = rg * 32 + mt * 16 + g * 4 + r;
    const float v = acc[r];
    of32[(long)k * 512 + n] = v;
    const __bf16 t1 = (__bf16)v;
    const float r1 = v - (float)t1;
    const __bf16 t2 = (__bf16)r1;
    const long fi = (((long)(n >> 4) * 16 + (k >> 5)) * 64 + ((k >> 3) & 3) * 16 + (n & 15)) * 8 + (k & 7);
    ofr[fi] = t1;
    ofr[TS + fi] = t2;
    ofr[2 * TS + fi] = (__bf16)(r1 - (float)t2);
  }
}

// Tree up-stage task (LDS-staged A): out[p] = in[2p] @ M + in[2p+1].
__device__ __forceinline__ void pair_dev(int b, const float* __restrict__ in,
                                         const __bf16* __restrict__ bf,
                                         float* __restrict__ outb, float* hbuf) {
  const int p = b >> 3, cs = b & 7;
  const int tid = threadIdx.x, l = tid & 63, w = tid >> 6, g = l >> 4, li = l & 15;
  stage_sw(in + (long)(2 * p) * ST32, hbuf);
  __syncthreads();
  const int mt = w >> 2, ntg = cs * 4 + (w & 3);
  const f32x4 acc = lds_mm(hbuf, bf, mt, ntg);
  const float* addp = in + (long)(2 * p + 1) * ST32;
  float* outp = outb + (long)p * ST32;
  const int col = ntg * 16 + li;
#pragma unroll
  for (int r = 0; r < 4; ++r) {
    const int row = mt * 16 + g * 4 + r;
    outp[(long)row * 512 + col] = acc[r] + addp[(long)row * 512 + col];
  }
}

// ---- kernels --------------------------------------------------------------

// Split two fp32 512x512 matrices into 3 bf16 terms (MFMA B-fragment order).
__global__ __launch_bounds__(512) void k_split2(const float* __restrict__ m0,
                                                const float* __restrict__ m1,
                                                __bf16* __restrict__ f0,
                                                __bf16* __restrict__ f1) {
  const int bb = blockIdx.x;
  const float* m = (bb < 512) ? m0 : m1;
  __bf16* f = (bb < 512) ? f0 : f1;
  const int idx = (bb & 511) * 512 + threadIdx.x;
  const int j = idx & 7, l = (idx >> 3) & 63, kk = (idx >> 9) & 15, nt = idx >> 13;
  const int k = kk * 32 + (l >> 4) * 8 + j;
  const int n = nt * 16 + (l & 15);
  const float v = m[k * 512 + n];
  const __bf16 t1 = (__bf16)v;
  const float r1 = v - (float)t1;
  const __bf16 t2 = (__bf16)r1;
  f[idx] = t1;
  f[TS + idx] = t2;
  f[2 * TS + idx] = (__bf16)(r1 - (float)t2);
}

// xW remainder kernel (base = first M=64 tile index).
__global__ __launch_bounds__(512) void k_xw(const float* __restrict__ x,
                                            const __bf16* __restrict__ wf,
                                            float* __restrict__ out, int base) {
  __shared__ __align__(16) char smem[64 * PP * 2];
  xw_dev(base + blockIdx.x, x, wf, out, smem);
}

// Co-dispatch: blocks 0-127 advance squaring chain; blocks 128+ do xw tiles.
__global__ __launch_bounds__(512) void k_xwsq(const float* __restrict__ sqa,
                                              const __bf16* __restrict__ sqbf,
                                              float* __restrict__ sqo32,
                                              __bf16* __restrict__ sqofr,
                                              const float* __restrict__ x,
                                              const __bf16* __restrict__ wf,
                                              float* __restrict__ out, int base) {
  __shared__ __align__(16) char smem[64 * PP * 2];
  const int b = blockIdx.x;
  if (b < 128)
    sq_dev(b, sqa, sqbf, sqo32, sqofr, (float*)smem);
  else
    xw_dev(base + (b - 128), x, wf, out, smem);
}

// Co-dispatch: blocks 0-127 squaring; blocks 128+ tree up-stage.
__global__ __launch_bounds__(512) void k_combo(const float* __restrict__ sqa,
                                               const __bf16* __restrict__ sqbf,
                                               float* __restrict__ sqo32,
                                               __bf16* __restrict__ sqofr,
                                               const float* __restrict__ prin,
                                               const __bf16* __restrict__ prbf,
                                               float* __restrict__ prout) {
  __shared__ float hbuf[ST32];
  const int b = blockIdx.x;
  if (b < 128)
    sq_dev(b, sqa, sqbf, sqo32, sqofr, hbuf);
  else
    pair_dev(b - 128, prin, prbf, prout, hbuf);
}

// Level-0 up-sweep: h = xw[t0]; 1 single step; 3 double steps. 2-term R.
__global__ __launch_bounds__(1024) void k_local(const float* __restrict__ xw,
                                                const __bf16* __restrict__ rf,
                                                const __bf16* __restrict__ r2f,
                                                float* __restrict__ sout) {
  __shared__ __bf16 Phi[32 * PP], Plo[32 * PP], Qhi[32 * PP], Qlo[32 * PP];
  const long c = blockIdx.x;
  stage32p(xw + c * 8 * UDIM, TDIM * UDIM, Phi, Plo);  // h = xw[t0]
  __syncthreads();
  pstep32<2, 3, true>(Phi, Plo, rf, xw + (c * 8 + 1) * UDIM, TDIM * UDIM);
  dstep(Phi, Plo, Qhi, Qlo, r2f, rf, xw, c * 8 + 2, c * 8 + 3);
  dstep(Phi, Plo, Qhi, Qlo, r2f, rf, xw, c * 8 + 4, c * 8 + 5);
  dstep(Phi, Plo, Qhi, Qlo, r2f, rf, xw, c * 8 + 6, c * 8 + 7);
  write_flat(Phi, Plo, sout + c * ST32);
}

// Final pass, with fused down-k=1:
//   even chunk c=2p:  entry = E1[p]
//   odd  chunk c=2p+1: entry = E1[p]@R^8 + S[2p]   (2-term R^8)
// then 8 serial steps (1-term R, 2 products) writing h into out.
__global__ __launch_bounds__(1024) void k_fix0(const float* __restrict__ e1,
                                               const float* __restrict__ sbuf,
                                               float* out,
                                               const __bf16* __restrict__ rf,
                                               const __bf16* __restrict__ r8f) {
  __shared__ __bf16 Phi[32 * PP], Plo[32 * PP];
  const long c = blockIdx.x;
  stage32p(e1 + (c >> 1) * ST32, 512, Phi, Plo);
  __syncthreads();
  if (c & 1)
    pstep32<2, 3, true>(Phi, Plo, r8f, sbuf + (c - 1) * ST32, 512);
  for (int j = 0; j < 8; ++j) {
    pstep32<1, 2, true>(Phi, Plo, rf, out + (c * 8 + j) * UDIM, TDIM * UDIM);
    write_bt(Phi, Plo, out, c * 8 + j);
  }
}

// Tree down-stage (LDS-staged parent), in place into child-level buffer:
//   ulev[2p+1] = epar[p] @ M + ulev[2p];  ulev[2p] = epar[p]
__global__ __launch_bounds__(512) void k_down(const float* __restrict__ epar,
                                              float* __restrict__ ulev,
                                              const __bf16* __restrict__ bf) {
  __shared__ float hbuf[ST32];
  const int p = blockIdx.x >> 3, cs = blockIdx.x & 7;
  const int tid = threadIdx.x, l = tid & 63, w = tid >> 6, g = l >> 4, li = l & 15;
  stage_sw(epar + (long)p * ST32, hbuf);
  __syncthreads();
  const int mt = w >> 2, ntg = cs * 4 + (w & 3);
  const f32x4 acc = lds_mm(hbuf, bf, mt, ntg);
  float* evp = ulev + (long)(2 * p) * ST32;
  float* outp = ulev + (long)(2 * p + 1) * ST32;
  const int col = ntg * 16 + li;
  float cp[4];
#pragma unroll
  for (int r = 0; r < 4; ++r) {
    const int row = mt * 16 + g * 4 + r;
    const long off = (long)row * 512 + col;
    cp[r] = hbuf[hidx(row, col)];     // = epar[p][row][col], exact
    outp[off] = acc[r] + evp[off];
  }
  __syncthreads();
#pragma unroll
  for (int r = 0; r < 4; ++r) {
    const int row = mt * 16 + g * 4 + r;
    evp[(long)row * 512 + col] = cp[r];
  }
}

extern "C" void kernel_launch(void* const* d_in, const int* in_sizes, int n_in,
                              void* d_out, int out_size, void* d_ws, size_t ws_size,
                              hipStream_t stream) {
  (void)in_sizes; (void)n_in; (void)out_size; (void)ws_size;
  const float* x  = (const float*)d_in[0];
  const float* W  = (const float*)d_in[1];
  const float* R  = (const float*)d_in[2];
  const float* h0 = (const float*)d_in[3];
  float* out = (float*)d_out;

  __bf16* F  = (__bf16*)d_ws;          // F[i] = frags of R^(2^i), i=0..10
  __bf16* Fw = F + 11 * FE;            // frags of W
  float* P1 = (float*)(Fw + FE);
  float* P2 = P1 + TS;
  float* Sbuf = P2 + TS;               // 256 chunk sums (S) -- preserved
  float* Ub[8];
  {
    float* up = Sbuf + 256 * ST32;
    for (int k = 1; k <= 7; ++k) { Ub[k] = up; up += (1L << (8 - k)) * ST32; }
  }

  k_split2<<<1024, 512, 0, stream>>>(W, R, Fw, F);

  // Head squarings co-dispatched with xw slices (256 M=64 tiles each):
  //   F[1]=R^2 ; F[2]=R^4 ; F[3]=R^8  (fp32 ping-pong, frag split fused)
  k_xwsq<<<384, 512, 0, stream>>>(R, F, P1, F + FE, x, Fw, out, 0);
  k_xwsq<<<384, 512, 0, stream>>>(P1, F + FE, P2, F + 2L * FE, x, Fw, out, 256);
  k_xwsq<<<384, 512, 0, stream>>>(P2, F + 2L * FE, P1, F + 3L * FE, x, Fw, out, 512);
  k_xw<<<256, 512, 0, stream>>>(x, Fw, out, 768);

  k_local<<<256, 1024, 0, stream>>>(out, F, F + FE, Sbuf);

  // phases k=1..7: sq (F[k+3] <- F[k+2], fp32 ping-pong) || tree-up stage k
  for (int k = 1; k <= 7; ++k) {
    const int i = k + 3;  // chain index being produced
    const float* sqa = (i & 1) ? P2 : P1;   // fp32 of R^(2^(i-1))
    float* sqo = (i & 1) ? P1 : P2;
    const float* prin = (k == 1) ? Sbuf : Ub[k - 1];
    const int npr = (1 << (8 - k)) * 8;
    k_combo<<<128 + npr, 512, 0, stream>>>(sqa, F + (long)(i - 1) * FE, sqo,
                                           F + (long)i * FE, prin,
                                           F + (long)(k + 2) * FE, Ub[k]);
  }

  // down-sweep k=7..2 (k=1 fused into fix0); E1 lands in Ub[1], S stays in Sbuf
  k_down<<<8, 512, 0, stream>>>(h0, Ub[7], F + 10L * FE);
  for (int k = 7; k >= 2; --k)
    k_down<<<(1 << (8 - k)) * 8, 512, 0, stream>>>(Ub[k], Ub[k - 1], F + (long)(k + 2) * FE);

  k_fix0<<<256, 1024, 0, stream>>>(Ub[1], Sbuf, out, F, F + 3L * FE);
}